// Round 1
// 199.586 us; speedup vs baseline: 1.0488x; 1.0488x over previous
//
#include <hip/hip_runtime.h>
#include <math.h>

// Problem constants
#define BATCH 4
#define HH 56
#define WW 56
#define DMODEL 256
#define NHEADS 8
#define HD 32
#define NNB 49               // 7x7 neighborhood
#define NTOK (BATCH*HH*WW)   // 12544

#define HALO 22              // 16 + 2*3
#define NHTOK (HALO*HALO)    // 484
// KV_PAD must keep rows 16B-aligned for ds_*_b128: stride (bf16) must be a
// multiple of 8. 40 (80B) aligned & proven; 36 broke b128 codegen (R9, 3.5x).
#define KV_PAD 40

typedef __attribute__((ext_vector_type(8))) short s16x8;
typedef __attribute__((ext_vector_type(4))) float f32x4;
typedef __attribute__((ext_vector_type(2))) float f32x2;

__device__ inline unsigned short f2b(float f) {
    union { float f; unsigned int u; } v; v.f = f;
    unsigned int r = v.u + 0x7FFF + ((v.u >> 16) & 1);  // RNE
    return (unsigned short)(r >> 16);
}
__device__ inline float b2f(unsigned short u) {
    union { float f; unsigned int u; } v; v.u = ((unsigned int)u) << 16;
    return v.f;
}

// unpack 2 packed bf16 (one u32) -> f32x2 {elem0, elem1}; 2 VALU ops
__device__ __forceinline__ f32x2 unpk(unsigned int u) {
    union { unsigned int u; float f; } lo, hi;
    lo.u = u << 16;
    hi.u = u & 0xffff0000u;
    return f32x2{lo.f, hi.f};
}

// packed fma -> v_pk_fma_f32 (VOP3P, gfx90a+); 1 issue for 2 lanes of math
__device__ __forceinline__ f32x2 pk_fma(f32x2 a, f32x2 b, f32x2 c) {
#if __has_builtin(__builtin_elementwise_fma)
    return __builtin_elementwise_fma(a, b, c);
#else
    return f32x2{fmaf(a.x, b.x, c.x), fmaf(a.y, b.y, c.y)};
#endif
}

// async 16B/lane global->LDS copy; lds base wave-uniform, lane i -> base+i*16
__device__ __forceinline__ void async16(const unsigned short* g, unsigned short* l) {
    __builtin_amdgcn_global_load_lds(
        (const __attribute__((address_space(1))) unsigned int*)g,
        (__attribute__((address_space(3))) unsigned int*)l, 16, 0, 0);
}

// ---------------------------------------------------------------------------
// prep: cast x to bf16 (8 elems/thread, vectorized) + cast+transpose weights
// to [N][K] bf16. x-cast feeds the qkv GEMM's async16 bf16 path, which
// removes the AF32 reg-staging + per-kstep f2b VALU storm (R0 theory).
// ---------------------------------------------------------------------------
#define XCAST_BLOCKS 1568    // NTOK*256/8/256
__global__ __launch_bounds__(256)
void prep_kernel(const float* __restrict__ x,
                 const float* __restrict__ Wq, const float* __restrict__ Wp,
                 const float* __restrict__ W1, const float* __restrict__ W2,
                 unsigned short* __restrict__ xb,
                 unsigned short* __restrict__ Wqb, unsigned short* __restrict__ Wpb,
                 unsigned short* __restrict__ W1b, unsigned short* __restrict__ W2b)
{
    if (blockIdx.x < XCAST_BLOCKS) {
        const int i = blockIdx.x * 256 + threadIdx.x;   // 8 floats each
        const float4* xp = (const float4*)x + (size_t)i * 2;
        const float4 a = xp[0], b = xp[1];
        s16x8 o;
        o[0] = (short)f2b(a.x); o[1] = (short)f2b(a.y);
        o[2] = (short)f2b(a.z); o[3] = (short)f2b(a.w);
        o[4] = (short)f2b(b.x); o[5] = (short)f2b(b.y);
        o[6] = (short)f2b(b.z); o[7] = (short)f2b(b.w);
        *((s16x8*)xb + i) = o;
        return;
    }
    int i = (blockIdx.x - XCAST_BLOCKS) * 256 + threadIdx.x;
    if (i < 196608) {            // W_qkv: K=256, N=768
        int n = i >> 8, k = i & 255;
        Wqb[i] = f2b(Wq[k * 768 + n]);
    } else if ((i -= 196608) < 65536) {   // W_proj: K=256, N=256
        int n = i >> 8, k = i & 255;
        Wpb[i] = f2b(Wp[k * 256 + n]);
    } else if ((i -= 65536) < 262144) {   // W1: K=256, N=1024
        int n = i >> 8, k = i & 255;
        W1b[i] = f2b(W1[k * 1024 + n]);
    } else {                              // W2: K=1024, N=256
        i -= 262144;
        int n = i >> 10, k = i & 1023;
        W2b[i] = f2b(W2[k * 256 + n]);
    }
}

// ---------------------------------------------------------------------------
// bf16 MFMA GEMM, m97-style staging. 128xBN tile (BN=128), 4 waves.
// A: bf16 [M][K] via global_load_lds, or f32 (AF32) with fused cast.
// B: bf16 [N][K] via global_load_lds. LDS unpadded [row][64] (m97 layout).
// ---------------------------------------------------------------------------
template<int BN, bool AF32>
__global__ __launch_bounds__(256)
void gemm_k(const unsigned short* __restrict__ Ab, const float* __restrict__ Af,
            const unsigned short* __restrict__ Bt, const float* __restrict__ bias,
            float* __restrict__ outf, unsigned short* __restrict__ outb,
            int M, int N, int K, int relu)
{
    constexpr int NB  = BN / 32;
    constexpr int BPW = BN / 32;
    __shared__ unsigned short As[128 * 64];
    __shared__ unsigned short Bs[BN * 64];

    const int tid = threadIdx.x;
    const int bm = blockIdx.y * 128, bn = blockIdx.x * BN;
    const int wid = tid >> 6, lane = tid & 63;
    const int wm = (wid >> 1) * 64, wn = (wid & 1) * (BN / 2);
    const int row16 = lane & 15, quad = lane >> 4;
    const int crow = lane >> 3, ck8 = (lane & 7) * 8;

    f32x4 acc[4][NB] = {};

    for (int k0 = 0; k0 < K; k0 += 64) {
        float4 fv[8];
        if (AF32) {
            const float* g = Af + (size_t)(bm + (tid >> 1)) * K + k0 + (tid & 1) * 32;
            #pragma unroll
            for (int u = 0; u < 8; ++u) fv[u] = *(const float4*)(g + u * 4);
        }
        __syncthreads();
        if (AF32) {
            unsigned short* d = As + (tid >> 1) * 64 + (tid & 1) * 32;
            #pragma unroll
            for (int u = 0; u < 4; ++u) {
                s16x8 o;
                o[0] = (short)f2b(fv[2*u].x);   o[1] = (short)f2b(fv[2*u].y);
                o[2] = (short)f2b(fv[2*u].z);   o[3] = (short)f2b(fv[2*u].w);
                o[4] = (short)f2b(fv[2*u+1].x); o[5] = (short)f2b(fv[2*u+1].y);
                o[6] = (short)f2b(fv[2*u+1].z); o[7] = (short)f2b(fv[2*u+1].w);
                *(s16x8*)(d + u * 8) = o;
            }
        } else {
            #pragma unroll
            for (int c = 0; c < 4; ++c) {
                const int ch = wid * 4 + c;
                async16(Ab + (size_t)(bm + ch * 8 + crow) * K + k0 + ck8, As + ch * 512);
            }
        }
        #pragma unroll
        for (int c = 0; c < BPW; ++c) {
            const int ch = wid * BPW + c;
            async16(Bt + (size_t)(bn + ch * 8 + crow) * K + k0 + ck8, Bs + ch * 512);
        }
        __syncthreads();

        #pragma unroll
        for (int kc = 0; kc < 2; ++kc) {
            s16x8 af[4], bf[NB];
            #pragma unroll
            for (int i = 0; i < 4; ++i)
                af[i] = *(const s16x8*)(As + (wm + i * 16 + row16) * 64 + kc * 32 + quad * 8);
            #pragma unroll
            for (int j = 0; j < NB; ++j)
                bf[j] = *(const s16x8*)(Bs + (wn + j * 16 + row16) * 64 + kc * 32 + quad * 8);
            #pragma unroll
            for (int i = 0; i < 4; ++i)
                #pragma unroll
                for (int j = 0; j < NB; ++j)
                    acc[i][j] = __builtin_amdgcn_mfma_f32_16x16x32_bf16(af[i], bf[j], acc[i][j], 0, 0, 0);
        }
    }

    #pragma unroll
    for (int j = 0; j < NB; ++j) {
        const int col = bn + wn + j * 16 + row16;
        const float bb = bias[col];
        #pragma unroll
        for (int i = 0; i < 4; ++i) {
            const int r0 = bm + wm + i * 16 + quad * 4;
            #pragma unroll
            for (int reg = 0; reg < 4; ++reg) {
                float v = acc[i][j][reg] + bb;
                if (relu) v = fmaxf(v, 0.f);
                if (outf) outf[(size_t)(r0 + reg) * N + col] = v;
                if (outb) outb[(size_t)(r0 + reg) * N + col] = f2b(v);
            }
        }
    }
}

// ---------------------------------------------------------------------------
// Fused GEMM (N=256 full-row tile) + residual add + LayerNorm.
// out = LN(resid + A@Bt^T + bias) * g + beta.
// Tile 32 rows x 256 cols (grid M/32 = 392 >= 256 CUs), 4 waves; wave w
// covers cols [64w, 64w+64), all 32 rows.
// ---------------------------------------------------------------------------
__global__ __launch_bounds__(256)
void gemm_ln(const unsigned short* __restrict__ Ab, const unsigned short* __restrict__ Bt,
             const float* __restrict__ bias, const float* __restrict__ resid,
             const float* __restrict__ g, const float* __restrict__ beta,
             float* __restrict__ outf, unsigned short* __restrict__ outb, int K)
{
    __shared__ unsigned short As[32 * 64];    // 4 KB (reused for LN reduction)
    __shared__ unsigned short Bs[256 * 64];   // 32 KB

    const int tid = threadIdx.x;
    const int bm = blockIdx.x * 32;
    const int wid = tid >> 6, lane = tid & 63;
    const int wn = wid * 64;
    const int row16 = lane & 15, quad = lane >> 4;
    const int crow = lane >> 3, ck8 = (lane & 7) * 8;

    f32x4 acc[2][4] = {};

    for (int k0 = 0; k0 < K; k0 += 64) {
        __syncthreads();
        // 36 chunks: 4 A (32 rows) + 32 B (256 rows); 9 per wave
        #pragma unroll
        for (int c = 0; c < 9; ++c) {
            const int ch = wid * 9 + c;
            if (ch < 4) {
                async16(Ab + (size_t)(bm + ch * 8 + crow) * K + k0 + ck8, As + ch * 512);
            } else {
                const int bc = ch - 4;
                async16(Bt + (size_t)(bc * 8 + crow) * K + k0 + ck8, Bs + bc * 512);
            }
        }
        __syncthreads();

        #pragma unroll
        for (int kc = 0; kc < 2; ++kc) {
            s16x8 af[2], bf[4];
            #pragma unroll
            for (int i = 0; i < 2; ++i)
                af[i] = *(const s16x8*)(As + (i * 16 + row16) * 64 + kc * 32 + quad * 8);
            #pragma unroll
            for (int j = 0; j < 4; ++j)
                bf[j] = *(const s16x8*)(Bs + (wn + j * 16 + row16) * 64 + kc * 32 + quad * 8);
            #pragma unroll
            for (int i = 0; i < 2; ++i)
                #pragma unroll
                for (int j = 0; j < 4; ++j)
                    acc[i][j] = __builtin_amdgcn_mfma_f32_16x16x32_bf16(af[i], bf[j], acc[i][j], 0, 0, 0);
        }
    }

    // ---- epilogue: bias + residual, in-register
    float bb[4], gv[4], bev[4];
    #pragma unroll
    for (int j = 0; j < 4; ++j) {
        const int col = wn + j * 16 + row16;
        bb[j] = bias[col]; gv[j] = g[col]; bev[j] = beta[col];
    }
    #pragma unroll
    for (int i = 0; i < 2; ++i) {
        #pragma unroll
        for (int reg = 0; reg < 4; ++reg) {
            const size_t rb = (size_t)(bm + i * 16 + quad * 4 + reg) * 256;
            #pragma unroll
            for (int j = 0; j < 4; ++j)
                acc[i][j][reg] += bb[j] + resid[rb + wn + j * 16 + row16];
        }
    }

    // ---- per-row sum / sumsq: reduce across row16 (16 lanes), then LDS
    __syncthreads();                      // all MFMA reads of As done
    float* red = (float*)As;              // [32 rows][4 waves][2]
    #pragma unroll
    for (int i = 0; i < 2; ++i) {
        #pragma unroll
        for (int reg = 0; reg < 4; ++reg) {
            float s1 = 0.f, s2 = 0.f;
            #pragma unroll
            for (int j = 0; j < 4; ++j) {
                const float t = acc[i][j][reg];
                s1 += t; s2 += t * t;
            }
            #pragma unroll
            for (int o = 1; o < 16; o <<= 1) {
                s1 += __shfl_xor(s1, o, 64);
                s2 += __shfl_xor(s2, o, 64);
            }
            if (row16 == 0) {
                const int lrow = i * 16 + quad * 4 + reg;
                red[lrow * 8 + wid * 2]     = s1;
                red[lrow * 8 + wid * 2 + 1] = s2;
            }
        }
    }
    __syncthreads();
    float* stats = red + 256;             // [32][2] = m, invstd
    if (tid < 32) {
        const float S1 = red[tid*8] + red[tid*8+2] + red[tid*8+4] + red[tid*8+6];
        const float S2 = red[tid*8+1] + red[tid*8+3] + red[tid*8+5] + red[tid*8+7];
        const float m = S1 * (1.0f / 256.0f);
        const float var = S2 * (1.0f / 256.0f) - m * m;
        stats[tid * 2]     = m;
        stats[tid * 2 + 1] = rsqrtf(var + 1e-5f);
    }
    __syncthreads();

    // ---- normalize + store
    #pragma unroll
    for (int i = 0; i < 2; ++i) {
        #pragma unroll
        for (int reg = 0; reg < 4; ++reg) {
            const int lrow = i * 16 + quad * 4 + reg;
            const float m = stats[lrow * 2], r = stats[lrow * 2 + 1];
            const size_t rb = (size_t)(bm + lrow) * 256;
            #pragma unroll
            for (int j = 0; j < 4; ++j) {
                const int col = wn + j * 16 + row16;
                const float o = (acc[i][j][reg] - m) * r * gv[j] + bev[j];
                outf[rb + col] = o;
                if (outb) outb[rb + col] = f2b(o);
            }
        }
    }
}

// ---------------------------------------------------------------------------
// Tiled neighborhood attention (R6/R10 proven): block = (16x16 tile, head),
// 256 threads, 1 query/lane; K,V halo in LDS (pad 40, 16B-aligned rows);
// fused no-max softmax pass. R0-polish: packed bf16 unpack (shl+and per
// pair) + v_pk_fma_f32 halves the FMA issue count (~134 -> ~100 VALU/nb).
// ---------------------------------------------------------------------------
__global__ __launch_bounds__(256, 2)
void natt_kernel(const unsigned short* __restrict__ qkvb, unsigned short* __restrict__ att)
{
    const int blk  = blockIdx.x;          // 4*16*8 = 512
    const int head = blk & 7;
    const int t2   = blk >> 3;
    const int tile = t2 & 15;
    const int b    = t2 >> 4;
    const int r0 = (tile >> 2) * 16, c0 = (tile & 3) * 16;
    const int hs = min(max(r0 - 3, 0), 34);
    const int ws = min(max(c0 - 3, 0), 34);

    __shared__ unsigned short Ks[NHTOK * KV_PAD];
    __shared__ unsigned short Vs[NHTOK * KV_PAD];

    const int tid = threadIdx.x;

    #pragma unroll
    for (int it = 0; it < 8; ++it) {
        const int t = it * 64 + (tid >> 2);
        if (t < NHTOK) {
            const int hr = t / HALO, hc = t - hr * HALO;
            const size_t rb = ((size_t)((b * 56 + hs + hr) * 56 + (ws + hc))) * 768;
            const int d8 = (tid & 3) * 8;
            *(s16x8*)(Ks + t * KV_PAD + d8) = *(const s16x8*)(qkvb + rb + 256 + head * 32 + d8);
            *(s16x8*)(Vs + t * KV_PAD + d8) = *(const s16x8*)(qkvb + rb + 512 + head * 32 + d8);
        }
    }

    const int qh = min(r0 + (tid >> 4), 55);
    const int qw = min(c0 + (tid & 15), 55);
    const int tok = (b * 56 + qh) * 56 + qw;
    const int ro = min(max(qh - 3, 0), 49) - hs;
    const int co = min(max(qw - 3, 0), 49) - ws;

    f32x2 qf[16];
    {
        const unsigned int* qp = (const unsigned int*)(qkvb + (size_t)tok * 768 + head * 32);
        #pragma unroll
        for (int p = 0; p < 16; ++p)
            qf[p] = unpk(qp[p]) * 0.17677669529663687f;
    }
    __syncthreads();

    f32x2 acc[16] = {};
    float sum = 0.f;
    for (int i = 0; i < 7; ++i) {
        const int trow = (ro + i) * HALO + co;
        #pragma unroll
        for (int j = 0; j < 7; ++j) {
            const unsigned int* kp = (const unsigned int*)(Ks + (trow + j) * KV_PAD);
            const unsigned int* vp = (const unsigned int*)(Vs + (trow + j) * KV_PAD);
            const uint4 ka = *(const uint4*)(kp);
            const uint4 kb = *(const uint4*)(kp + 4);
            const uint4 kc = *(const uint4*)(kp + 8);
            const uint4 kd = *(const uint4*)(kp + 12);
            const uint4 va = *(const uint4*)(vp);
            const uint4 vb = *(const uint4*)(vp + 4);
            const uint4 vc = *(const uint4*)(vp + 8);
            const uint4 vd = *(const uint4*)(vp + 12);
            // QK dot: 16 pk_fma, two parallel chains (8 deep each)
            f32x2 sa = {0.f, 0.f}, sb = {0.f, 0.f};
            sa = pk_fma(qf[0],  unpk(ka.x), sa);  sb = pk_fma(qf[1],  unpk(ka.y), sb);
            sa = pk_fma(qf[2],  unpk(ka.z), sa);  sb = pk_fma(qf[3],  unpk(ka.w), sb);
            sa = pk_fma(qf[4],  unpk(kb.x), sa);  sb = pk_fma(qf[5],  unpk(kb.y), sb);
            sa = pk_fma(qf[6],  unpk(kb.z), sa);  sb = pk_fma(qf[7],  unpk(kb.w), sb);
            sa = pk_fma(qf[8],  unpk(kc.x), sa);  sb = pk_fma(qf[9],  unpk(kc.y), sb);
            sa = pk_fma(qf[10], unpk(kc.z), sa);  sb = pk_fma(qf[11], unpk(kc.w), sb);
            sa = pk_fma(qf[12], unpk(kd.x), sa);  sb = pk_fma(qf[13], unpk(kd.y), sb);
            sa = pk_fma(qf[14], unpk(kd.z), sa);  sb = pk_fma(qf[15], unpk(kd.w), sb);
            const float p = __expf(sa.x + sa.y + sb.x + sb.y);
            sum += p;
            const f32x2 pv = {p, p};
            acc[0]  = pk_fma(pv, unpk(va.x), acc[0]);
            acc[1]  = pk_fma(pv, unpk(va.y), acc[1]);
            acc[2]  = pk_fma(pv, unpk(va.z), acc[2]);
            acc[3]  = pk_fma(pv, unpk(va.w), acc[3]);
            acc[4]  = pk_fma(pv, unpk(vb.x), acc[4]);
            acc[5]  = pk_fma(pv, unpk(vb.y), acc[5]);
            acc[6]  = pk_fma(pv, unpk(vb.z), acc[6]);
            acc[7]  = pk_fma(pv, unpk(vb.w), acc[7]);
            acc[8]  = pk_fma(pv, unpk(vc.x), acc[8]);
            acc[9]  = pk_fma(pv, unpk(vc.y), acc[9]);
            acc[10] = pk_fma(pv, unpk(vc.z), acc[10]);
            acc[11] = pk_fma(pv, unpk(vc.w), acc[11]);
            acc[12] = pk_fma(pv, unpk(vd.x), acc[12]);
            acc[13] = pk_fma(pv, unpk(vd.y), acc[13]);
            acc[14] = pk_fma(pv, unpk(vd.z), acc[14]);
            acc[15] = pk_fma(pv, unpk(vd.w), acc[15]);
        }
    }
    const float inv = 1.0f / sum;

    unsigned short* op = att + (size_t)tok * DMODEL + head * 32;
    #pragma unroll
    for (int d4 = 0; d4 < 8; ++d4) {
        ushort4 o;
        o.x = f2b(acc[d4 * 2].x     * inv);
        o.y = f2b(acc[d4 * 2].y     * inv);
        o.z = f2b(acc[d4 * 2 + 1].x * inv);
        o.w = f2b(acc[d4 * 2 + 1].y * inv);
        *(ushort4*)(op + d4 * 4) = o;
    }
}

// ---------------------------------------------------------------------------
extern "C" void kernel_launch(void* const* d_in, const int* in_sizes, int n_in,
                              void* d_out, int out_size, void* d_ws, size_t ws_size,
                              hipStream_t stream)
{
    const float* x      = (const float*)d_in[0];
    const float* W_qkv  = (const float*)d_in[1];
    const float* b_qkv  = (const float*)d_in[2];
    const float* W_proj = (const float*)d_in[3];
    const float* b_proj = (const float*)d_in[4];
    const float* W1     = (const float*)d_in[5];
    const float* b1     = (const float*)d_in[6];
    const float* W2     = (const float*)d_in[7];
    const float* b2     = (const float*)d_in[8];
    const float* g1     = (const float*)d_in[9];
    const float* be1    = (const float*)d_in[10];
    const float* g2     = (const float*)d_in[11];
    const float* be2    = (const float*)d_in[12];
    float* out = (float*)d_out;

    char* ws = (char*)d_ws;
    const int M = NTOK;  // 12544

    unsigned short* qkvb = (unsigned short*)ws;                     // [M][768] bf16
    unsigned short* h    = (unsigned short*)ws;                     // [M][1024] bf16 (after qkvb dead)
    unsigned short* attb = (unsigned short*)(ws + 38535168);        // [M][256] bf16
    float*          xn   = (float*)(ws + 57802752);                 // [M][256] f32
    unsigned short* xnb  = (unsigned short*)(ws + 70647808);        // [M][256] bf16
    unsigned short* Wqb  = (unsigned short*)(ws + 77070336);
    unsigned short* Wpb  = Wqb + 196608;
    unsigned short* W1b  = Wpb + 65536;
    unsigned short* W2b  = W1b + 262144;
    unsigned short* xb   = (unsigned short*)(ws + 78643200);        // [M][256] bf16

    dim3 blk(256);

    // 0) cast x to bf16 + cast/transpose weights to bf16
    prep_kernel<<<dim3(XCAST_BLOCKS + 3072), blk, 0, stream>>>(
        x, W_qkv, W_proj, W1, W2, xb, Wqb, Wpb, W1b, W2b);

    // 1) qkvb = bf16(xb @ W_qkv + b_qkv)  — bf16 async16 path (no AF32 staging)
    gemm_k<128, false><<<dim3(6, 98), blk, 0, stream>>>(xb, nullptr, Wqb, b_qkv, nullptr, qkvb, M, 768, 256, 0);

    // 2) tiled neighborhood attention -> attb
    natt_kernel<<<dim3(512), blk, 0, stream>>>(qkvb, attb);

    // 3+4) xn = LN(x + attb @ W_proj + b_proj)  (f32 + bf16), fused
    gemm_ln<<<dim3(M / 32), blk, 0, stream>>>(attb, Wpb, b_proj, x, g1, be1, xn, xnb, 256);

    // 5) h = relu(xnb @ W1 + b1)  (bf16)
    gemm_k<128, false><<<dim3(8, 98), blk, 0, stream>>>(xnb, nullptr, W1b, b1, nullptr, h, M, 1024, 256, 1);

    // 6+7) out = LN(xn + h @ W2 + b2), fused
    gemm_ln<<<dim3(M / 32), blk, 0, stream>>>(h, W2b, b2, xn, g2, be2, out, nullptr, 1024);
}

// Round 2
// 199.160 us; speedup vs baseline: 1.0510x; 1.0021x over previous
//
#include <hip/hip_runtime.h>
#include <math.h>

// Problem constants
#define BATCH 4
#define HH 56
#define WW 56
#define DMODEL 256
#define NHEADS 8
#define HD 32
#define NNB 49               // 7x7 neighborhood
#define NTOK (BATCH*HH*WW)   // 12544

#define HALO 22              // 16 + 2*3
#define NHTOK (HALO*HALO)    // 484
// KV_PAD must keep rows 16B-aligned for ds_*_b128: stride (bf16) must be a
// multiple of 8. 40 (80B) aligned & proven; 36 broke b128 codegen (R9, 3.5x).
#define KV_PAD 40

typedef __attribute__((ext_vector_type(8))) short s16x8;
typedef __attribute__((ext_vector_type(4))) float f32x4;
typedef __attribute__((ext_vector_type(2))) float f32x2;

__device__ inline unsigned short f2b(float f) {
    union { float f; unsigned int u; } v; v.f = f;
    unsigned int r = v.u + 0x7FFF + ((v.u >> 16) & 1);  // RNE
    return (unsigned short)(r >> 16);
}
__device__ inline float b2f(unsigned short u) {
    union { float f; unsigned int u; } v; v.u = ((unsigned int)u) << 16;
    return v.f;
}

// unpack 2 packed bf16 (one u32) -> f32x2 {elem0, elem1}; 2 VALU ops
__device__ __forceinline__ f32x2 unpk(unsigned int u) {
    union { unsigned int u; float f; } lo, hi;
    lo.u = u << 16;
    hi.u = u & 0xffff0000u;
    return f32x2{lo.f, hi.f};
}

// packed fma -> v_pk_fma_f32 (VOP3P, gfx90a+); 1 issue for 2 lanes of math
__device__ __forceinline__ f32x2 pk_fma(f32x2 a, f32x2 b, f32x2 c) {
#if __has_builtin(__builtin_elementwise_fma)
    return __builtin_elementwise_fma(a, b, c);
#else
    return f32x2{fmaf(a.x, b.x, c.x), fmaf(a.y, b.y, c.y)};
#endif
}

// async 16B/lane global->LDS copy; lds base wave-uniform, lane i -> base+i*16
__device__ __forceinline__ void async16(const unsigned short* g, unsigned short* l) {
    __builtin_amdgcn_global_load_lds(
        (const __attribute__((address_space(1))) unsigned int*)g,
        (__attribute__((address_space(3))) unsigned int*)l, 16, 0, 0);
}

// ---------------------------------------------------------------------------
// prep: cast x to bf16 (8 elems/thread, vectorized) + cast+transpose weights
// to [N][K] bf16.
// ---------------------------------------------------------------------------
#define XCAST_BLOCKS 1568    // NTOK*256/8/256
__global__ __launch_bounds__(256)
void prep_kernel(const float* __restrict__ x,
                 const float* __restrict__ Wq, const float* __restrict__ Wp,
                 const float* __restrict__ W1, const float* __restrict__ W2,
                 unsigned short* __restrict__ xb,
                 unsigned short* __restrict__ Wqb, unsigned short* __restrict__ Wpb,
                 unsigned short* __restrict__ W1b, unsigned short* __restrict__ W2b)
{
    if (blockIdx.x < XCAST_BLOCKS) {
        const int i = blockIdx.x * 256 + threadIdx.x;   // 8 floats each
        const float4* xp = (const float4*)x + (size_t)i * 2;
        const float4 a = xp[0], b = xp[1];
        s16x8 o;
        o[0] = (short)f2b(a.x); o[1] = (short)f2b(a.y);
        o[2] = (short)f2b(a.z); o[3] = (short)f2b(a.w);
        o[4] = (short)f2b(b.x); o[5] = (short)f2b(b.y);
        o[6] = (short)f2b(b.z); o[7] = (short)f2b(b.w);
        *((s16x8*)xb + i) = o;
        return;
    }
    int i = (blockIdx.x - XCAST_BLOCKS) * 256 + threadIdx.x;
    if (i < 196608) {            // W_qkv: K=256, N=768
        int n = i >> 8, k = i & 255;
        Wqb[i] = f2b(Wq[k * 768 + n]);
    } else if ((i -= 196608) < 65536) {   // W_proj: K=256, N=256
        int n = i >> 8, k = i & 255;
        Wpb[i] = f2b(Wp[k * 256 + n]);
    } else if ((i -= 65536) < 262144) {   // W1: K=256, N=1024
        int n = i >> 8, k = i & 255;
        W1b[i] = f2b(W1[k * 1024 + n]);
    } else {                              // W2: K=1024, N=256
        i -= 262144;
        int n = i >> 10, k = i & 1023;
        W2b[i] = f2b(W2[k * 256 + n]);
    }
}

// ---------------------------------------------------------------------------
// bf16 MFMA GEMM, 128xBN tile (BN=128), 4 waves. R1: T3-minimum 2-phase
// double-buffer — stage tile t+1 BEFORE computing tile t; single barrier
// (with its implicit vmcnt(0) drain) lands AFTER compute, so HBM/L2 load
// latency overlaps MFMA instead of sitting naked on the critical path.
// A: bf16 [M][K], B: bf16 [N][K], both via global_load_lds.
// LDS 64 KB (2 x 16 KB x 2 buffers) -> 2 blocks/CU.
// ---------------------------------------------------------------------------
template<int BN>
__global__ __launch_bounds__(256)
void gemm_k(const unsigned short* __restrict__ Ab,
            const unsigned short* __restrict__ Bt, const float* __restrict__ bias,
            float* __restrict__ outf, unsigned short* __restrict__ outb,
            int M, int N, int K, int relu)
{
    constexpr int NB  = BN / 32;
    constexpr int BPW = BN / 32;
    __shared__ unsigned short As[2][128 * 64];
    __shared__ unsigned short Bs[2][BN * 64];

    const int tid = threadIdx.x;
    const int bm = blockIdx.y * 128, bn = blockIdx.x * BN;
    const int wid = tid >> 6, lane = tid & 63;
    const int wm = (wid >> 1) * 64, wn = (wid & 1) * (BN / 2);
    const int row16 = lane & 15, quad = lane >> 4;
    const int crow = lane >> 3, ck8 = (lane & 7) * 8;

    f32x4 acc[4][NB] = {};

    auto stage = [&](int buf, int k0) {
        #pragma unroll
        for (int c = 0; c < 4; ++c) {
            const int ch = wid * 4 + c;
            async16(Ab + (size_t)(bm + ch * 8 + crow) * K + k0 + ck8, As[buf] + ch * 512);
        }
        #pragma unroll
        for (int c = 0; c < BPW; ++c) {
            const int ch = wid * BPW + c;
            async16(Bt + (size_t)(bn + ch * 8 + crow) * K + k0 + ck8, Bs[buf] + ch * 512);
        }
    };
    auto compute = [&](int buf) {
        #pragma unroll
        for (int kc = 0; kc < 2; ++kc) {
            s16x8 af[4], bf[NB];
            #pragma unroll
            for (int i = 0; i < 4; ++i)
                af[i] = *(const s16x8*)(As[buf] + (wm + i * 16 + row16) * 64 + kc * 32 + quad * 8);
            #pragma unroll
            for (int j = 0; j < NB; ++j)
                bf[j] = *(const s16x8*)(Bs[buf] + (wn + j * 16 + row16) * 64 + kc * 32 + quad * 8);
            #pragma unroll
            for (int i = 0; i < 4; ++i)
                #pragma unroll
                for (int j = 0; j < NB; ++j)
                    acc[i][j] = __builtin_amdgcn_mfma_f32_16x16x32_bf16(af[i], bf[j], acc[i][j], 0, 0, 0);
        }
    };

    stage(0, 0);
    __syncthreads();
    for (int k0 = 0; k0 < K; k0 += 128) {      // K % 128 == 0 (256 / 1024)
        stage(1, k0 + 64);
        compute(0);
        __syncthreads();
        if (k0 + 128 < K) stage(0, k0 + 128);
        compute(1);
        __syncthreads();
    }

    #pragma unroll
    for (int j = 0; j < NB; ++j) {
        const int col = bn + wn + j * 16 + row16;
        const float bb = bias[col];
        #pragma unroll
        for (int i = 0; i < 4; ++i) {
            const int r0 = bm + wm + i * 16 + quad * 4;
            #pragma unroll
            for (int reg = 0; reg < 4; ++reg) {
                float v = acc[i][j][reg] + bb;
                if (relu) v = fmaxf(v, 0.f);
                if (outf) outf[(size_t)(r0 + reg) * N + col] = v;
                if (outb) outb[(size_t)(r0 + reg) * N + col] = f2b(v);
            }
        }
    }
}

// ---------------------------------------------------------------------------
// Fused GEMM (N=256 full-row tile) + residual add + LayerNorm.
// out = LN(resid + A@Bt^T + bias) * g + beta.
// Tile 32 rows x 256 cols, 4 waves; wave w covers cols [64w, 64w+64).
// R1: same 2-phase double-buffer as gemm_k. LDS 72 KB -> 2 blocks/CU.
// ---------------------------------------------------------------------------
__global__ __launch_bounds__(256)
void gemm_ln(const unsigned short* __restrict__ Ab, const unsigned short* __restrict__ Bt,
             const float* __restrict__ bias, const float* __restrict__ resid,
             const float* __restrict__ g, const float* __restrict__ beta,
             float* __restrict__ outf, unsigned short* __restrict__ outb, int K)
{
    __shared__ unsigned short As[2][32 * 64];    // 8 KB (buf0 reused for LN reduce)
    __shared__ unsigned short Bs[2][256 * 64];   // 64 KB

    const int tid = threadIdx.x;
    const int bm = blockIdx.x * 32;
    const int wid = tid >> 6, lane = tid & 63;
    const int wn = wid * 64;
    const int row16 = lane & 15, quad = lane >> 4;
    const int crow = lane >> 3, ck8 = (lane & 7) * 8;

    f32x4 acc[2][4] = {};

    auto stage = [&](int buf, int k0) {
        // 36 chunks: 4 A (32 rows) + 32 B (256 rows); 9 per wave
        #pragma unroll
        for (int c = 0; c < 9; ++c) {
            const int ch = wid * 9 + c;
            if (ch < 4) {
                async16(Ab + (size_t)(bm + ch * 8 + crow) * K + k0 + ck8, As[buf] + ch * 512);
            } else {
                const int bc = ch - 4;
                async16(Bt + (size_t)(bc * 8 + crow) * K + k0 + ck8, Bs[buf] + bc * 512);
            }
        }
    };
    auto compute = [&](int buf) {
        #pragma unroll
        for (int kc = 0; kc < 2; ++kc) {
            s16x8 af[2], bf[4];
            #pragma unroll
            for (int i = 0; i < 2; ++i)
                af[i] = *(const s16x8*)(As[buf] + (i * 16 + row16) * 64 + kc * 32 + quad * 8);
            #pragma unroll
            for (int j = 0; j < 4; ++j)
                bf[j] = *(const s16x8*)(Bs[buf] + (wn + j * 16 + row16) * 64 + kc * 32 + quad * 8);
            #pragma unroll
            for (int i = 0; i < 2; ++i)
                #pragma unroll
                for (int j = 0; j < 4; ++j)
                    acc[i][j] = __builtin_amdgcn_mfma_f32_16x16x32_bf16(af[i], bf[j], acc[i][j], 0, 0, 0);
        }
    };

    stage(0, 0);
    __syncthreads();
    for (int k0 = 0; k0 < K; k0 += 128) {      // K % 128 == 0 (256 / 1024)
        stage(1, k0 + 64);
        compute(0);
        __syncthreads();
        if (k0 + 128 < K) stage(0, k0 + 128);
        compute(1);
        __syncthreads();
    }

    // ---- epilogue: bias + residual, in-register
    float bb[4], gv[4], bev[4];
    #pragma unroll
    for (int j = 0; j < 4; ++j) {
        const int col = wn + j * 16 + row16;
        bb[j] = bias[col]; gv[j] = g[col]; bev[j] = beta[col];
    }
    #pragma unroll
    for (int i = 0; i < 2; ++i) {
        #pragma unroll
        for (int reg = 0; reg < 4; ++reg) {
            const size_t rb = (size_t)(bm + i * 16 + quad * 4 + reg) * 256;
            #pragma unroll
            for (int j = 0; j < 4; ++j)
                acc[i][j][reg] += bb[j] + resid[rb + wn + j * 16 + row16];
        }
    }

    // ---- per-row sum / sumsq: reduce across row16 (16 lanes), then LDS
    // (final loop barrier already ordered all LDS reads before this point)
    float* red = (float*)As[0];           // [32 rows][4 waves][2]
    #pragma unroll
    for (int i = 0; i < 2; ++i) {
        #pragma unroll
        for (int reg = 0; reg < 4; ++reg) {
            float s1 = 0.f, s2 = 0.f;
            #pragma unroll
            for (int j = 0; j < 4; ++j) {
                const float t = acc[i][j][reg];
                s1 += t; s2 += t * t;
            }
            #pragma unroll
            for (int o = 1; o < 16; o <<= 1) {
                s1 += __shfl_xor(s1, o, 64);
                s2 += __shfl_xor(s2, o, 64);
            }
            if (row16 == 0) {
                const int lrow = i * 16 + quad * 4 + reg;
                red[lrow * 8 + wid * 2]     = s1;
                red[lrow * 8 + wid * 2 + 1] = s2;
            }
        }
    }
    __syncthreads();
    float* stats = red + 256;             // [32][2] = m, invstd
    if (tid < 32) {
        const float S1 = red[tid*8] + red[tid*8+2] + red[tid*8+4] + red[tid*8+6];
        const float S2 = red[tid*8+1] + red[tid*8+3] + red[tid*8+5] + red[tid*8+7];
        const float m = S1 * (1.0f / 256.0f);
        const float var = S2 * (1.0f / 256.0f) - m * m;
        stats[tid * 2]     = m;
        stats[tid * 2 + 1] = rsqrtf(var + 1e-5f);
    }
    __syncthreads();

    // ---- normalize + store
    #pragma unroll
    for (int i = 0; i < 2; ++i) {
        #pragma unroll
        for (int reg = 0; reg < 4; ++reg) {
            const int lrow = i * 16 + quad * 4 + reg;
            const float m = stats[lrow * 2], r = stats[lrow * 2 + 1];
            const size_t rb = (size_t)(bm + lrow) * 256;
            #pragma unroll
            for (int j = 0; j < 4; ++j) {
                const int col = wn + j * 16 + row16;
                const float o = (acc[i][j][reg] - m) * r * gv[j] + bev[j];
                outf[rb + col] = o;
                if (outb) outb[rb + col] = f2b(o);
            }
        }
    }
}

// ---------------------------------------------------------------------------
// Tiled neighborhood attention: block = (16x16 tile, head), 256 threads,
// 1 query/lane; K,V halo in LDS (pad 40, 16B-aligned rows); fused no-max
// softmax; packed bf16 unpack + v_pk_fma_f32 (R0).
// ---------------------------------------------------------------------------
__global__ __launch_bounds__(256, 2)
void natt_kernel(const unsigned short* __restrict__ qkvb, unsigned short* __restrict__ att)
{
    const int blk  = blockIdx.x;          // 4*16*8 = 512
    const int head = blk & 7;
    const int t2   = blk >> 3;
    const int tile = t2 & 15;
    const int b    = t2 >> 4;
    const int r0 = (tile >> 2) * 16, c0 = (tile & 3) * 16;
    const int hs = min(max(r0 - 3, 0), 34);
    const int ws = min(max(c0 - 3, 0), 34);

    __shared__ unsigned short Ks[NHTOK * KV_PAD];
    __shared__ unsigned short Vs[NHTOK * KV_PAD];

    const int tid = threadIdx.x;

    #pragma unroll
    for (int it = 0; it < 8; ++it) {
        const int t = it * 64 + (tid >> 2);
        if (t < NHTOK) {
            const int hr = t / HALO, hc = t - hr * HALO;
            const size_t rb = ((size_t)((b * 56 + hs + hr) * 56 + (ws + hc))) * 768;
            const int d8 = (tid & 3) * 8;
            *(s16x8*)(Ks + t * KV_PAD + d8) = *(const s16x8*)(qkvb + rb + 256 + head * 32 + d8);
            *(s16x8*)(Vs + t * KV_PAD + d8) = *(const s16x8*)(qkvb + rb + 512 + head * 32 + d8);
        }
    }

    const int qh = min(r0 + (tid >> 4), 55);
    const int qw = min(c0 + (tid & 15), 55);
    const int tok = (b * 56 + qh) * 56 + qw;
    const int ro = min(max(qh - 3, 0), 49) - hs;
    const int co = min(max(qw - 3, 0), 49) - ws;

    f32x2 qf[16];
    {
        const unsigned int* qp = (const unsigned int*)(qkvb + (size_t)tok * 768 + head * 32);
        #pragma unroll
        for (int p = 0; p < 16; ++p)
            qf[p] = unpk(qp[p]) * 0.17677669529663687f;
    }
    __syncthreads();

    f32x2 acc[16] = {};
    float sum = 0.f;
    for (int i = 0; i < 7; ++i) {
        const int trow = (ro + i) * HALO + co;
        #pragma unroll
        for (int j = 0; j < 7; ++j) {
            const unsigned int* kp = (const unsigned int*)(Ks + (trow + j) * KV_PAD);
            const unsigned int* vp = (const unsigned int*)(Vs + (trow + j) * KV_PAD);
            const uint4 ka = *(const uint4*)(kp);
            const uint4 kb = *(const uint4*)(kp + 4);
            const uint4 kc = *(const uint4*)(kp + 8);
            const uint4 kd = *(const uint4*)(kp + 12);
            const uint4 va = *(const uint4*)(vp);
            const uint4 vb = *(const uint4*)(vp + 4);
            const uint4 vc = *(const uint4*)(vp + 8);
            const uint4 vd = *(const uint4*)(vp + 12);
            // QK dot: 16 pk_fma, two parallel chains (8 deep each)
            f32x2 sa = {0.f, 0.f}, sb = {0.f, 0.f};
            sa = pk_fma(qf[0],  unpk(ka.x), sa);  sb = pk_fma(qf[1],  unpk(ka.y), sb);
            sa = pk_fma(qf[2],  unpk(ka.z), sa);  sb = pk_fma(qf[3],  unpk(ka.w), sb);
            sa = pk_fma(qf[4],  unpk(kb.x), sa);  sb = pk_fma(qf[5],  unpk(kb.y), sb);
            sa = pk_fma(qf[6],  unpk(kb.z), sa);  sb = pk_fma(qf[7],  unpk(kb.w), sb);
            sa = pk_fma(qf[8],  unpk(kc.x), sa);  sb = pk_fma(qf[9],  unpk(kc.y), sb);
            sa = pk_fma(qf[10], unpk(kc.z), sa);  sb = pk_fma(qf[11], unpk(kc.w), sb);
            sa = pk_fma(qf[12], unpk(kd.x), sa);  sb = pk_fma(qf[13], unpk(kd.y), sb);
            sa = pk_fma(qf[14], unpk(kd.z), sa);  sb = pk_fma(qf[15], unpk(kd.w), sb);
            const float p = __expf(sa.x + sa.y + sb.x + sb.y);
            sum += p;
            const f32x2 pv = {p, p};
            acc[0]  = pk_fma(pv, unpk(va.x), acc[0]);
            acc[1]  = pk_fma(pv, unpk(va.y), acc[1]);
            acc[2]  = pk_fma(pv, unpk(va.z), acc[2]);
            acc[3]  = pk_fma(pv, unpk(va.w), acc[3]);
            acc[4]  = pk_fma(pv, unpk(vb.x), acc[4]);
            acc[5]  = pk_fma(pv, unpk(vb.y), acc[5]);
            acc[6]  = pk_fma(pv, unpk(vb.z), acc[6]);
            acc[7]  = pk_fma(pv, unpk(vb.w), acc[7]);
            acc[8]  = pk_fma(pv, unpk(vc.x), acc[8]);
            acc[9]  = pk_fma(pv, unpk(vc.y), acc[9]);
            acc[10] = pk_fma(pv, unpk(vc.z), acc[10]);
            acc[11] = pk_fma(pv, unpk(vc.w), acc[11]);
            acc[12] = pk_fma(pv, unpk(vd.x), acc[12]);
            acc[13] = pk_fma(pv, unpk(vd.y), acc[13]);
            acc[14] = pk_fma(pv, unpk(vd.z), acc[14]);
            acc[15] = pk_fma(pv, unpk(vd.w), acc[15]);
        }
    }
    const float inv = 1.0f / sum;

    unsigned short* op = att + (size_t)tok * DMODEL + head * 32;
    #pragma unroll
    for (int d4 = 0; d4 < 8; ++d4) {
        ushort4 o;
        o.x = f2b(acc[d4 * 2].x     * inv);
        o.y = f2b(acc[d4 * 2].y     * inv);
        o.z = f2b(acc[d4 * 2 + 1].x * inv);
        o.w = f2b(acc[d4 * 2 + 1].y * inv);
        *(ushort4*)(op + d4 * 4) = o;
    }
}

// ---------------------------------------------------------------------------
extern "C" void kernel_launch(void* const* d_in, const int* in_sizes, int n_in,
                              void* d_out, int out_size, void* d_ws, size_t ws_size,
                              hipStream_t stream)
{
    const float* x      = (const float*)d_in[0];
    const float* W_qkv  = (const float*)d_in[1];
    const float* b_qkv  = (const float*)d_in[2];
    const float* W_proj = (const float*)d_in[3];
    const float* b_proj = (const float*)d_in[4];
    const float* W1     = (const float*)d_in[5];
    const float* b1     = (const float*)d_in[6];
    const float* W2     = (const float*)d_in[7];
    const float* b2     = (const float*)d_in[8];
    const float* g1     = (const float*)d_in[9];
    const float* be1    = (const float*)d_in[10];
    const float* g2     = (const float*)d_in[11];
    const float* be2    = (const float*)d_in[12];
    float* out = (float*)d_out;

    char* ws = (char*)d_ws;
    const int M = NTOK;  // 12544

    unsigned short* qkvb = (unsigned short*)ws;                     // [M][768] bf16
    unsigned short* h    = (unsigned short*)ws;                     // [M][1024] bf16 (after qkvb dead)
    unsigned short* attb = (unsigned short*)(ws + 38535168);        // [M][256] bf16
    float*          xn   = (float*)(ws + 57802752);                 // [M][256] f32
    unsigned short* xnb  = (unsigned short*)(ws + 70647808);        // [M][256] bf16
    unsigned short* Wqb  = (unsigned short*)(ws + 77070336);
    unsigned short* Wpb  = Wqb + 196608;
    unsigned short* W1b  = Wpb + 65536;
    unsigned short* W2b  = W1b + 262144;
    unsigned short* xb   = (unsigned short*)(ws + 78643200);        // [M][256] bf16

    dim3 blk(256);

    // 0) cast x to bf16 + cast/transpose weights to bf16
    prep_kernel<<<dim3(XCAST_BLOCKS + 3072), blk, 0, stream>>>(
        x, W_qkv, W_proj, W1, W2, xb, Wqb, Wpb, W1b, W2b);

    // 1) qkvb = bf16(xb @ W_qkv + b_qkv)
    gemm_k<128><<<dim3(6, 98), blk, 0, stream>>>(xb, Wqb, b_qkv, nullptr, qkvb, M, 768, 256, 0);

    // 2) tiled neighborhood attention -> attb
    natt_kernel<<<dim3(512), blk, 0, stream>>>(qkvb, attb);

    // 3+4) xn = LN(x + attb @ W_proj + b_proj)  (f32 + bf16), fused
    gemm_ln<<<dim3(M / 32), blk, 0, stream>>>(attb, Wpb, b_proj, x, g1, be1, xn, xnb, 256);

    // 5) h = relu(xnb @ W1 + b1)  (bf16)
    gemm_k<128><<<dim3(8, 98), blk, 0, stream>>>(xnb, W1b, b1, nullptr, h, M, 1024, 256, 1);

    // 6+7) out = LN(xn + h @ W2 + b2), fused
    gemm_ln<<<dim3(M / 32), blk, 0, stream>>>(h, W2b, b2, xn, g2, be2, out, nullptr, 1024);
}

// Round 3
// 194.823 us; speedup vs baseline: 1.0744x; 1.0223x over previous
//
#include <hip/hip_runtime.h>
#include <math.h>

// Problem constants
#define BATCH 4
#define HH 56
#define WW 56
#define DMODEL 256
#define NHEADS 8
#define HD 32
#define NNB 49               // 7x7 neighborhood
#define NTOK (BATCH*HH*WW)   // 12544

#define HALO 22              // 16 + 2*3
#define NHTOK (HALO*HALO)    // 484
// KV_PAD must keep rows 16B-aligned for ds_*_b128: stride (bf16) must be a
// multiple of 8. 40 (80B) aligned & proven; 36 broke b128 codegen (R9, 3.5x).
#define KV_PAD 40

typedef __attribute__((ext_vector_type(8))) short s16x8;
typedef __attribute__((ext_vector_type(4))) float f32x4;
typedef __attribute__((ext_vector_type(2))) float f32x2;

__device__ inline unsigned short f2b(float f) {
    union { float f; unsigned int u; } v; v.f = f;
    unsigned int r = v.u + 0x7FFF + ((v.u >> 16) & 1);  // RNE
    return (unsigned short)(r >> 16);
}
__device__ inline float b2f(unsigned short u) {
    union { float f; unsigned int u; } v; v.u = ((unsigned int)u) << 16;
    return v.f;
}

// unpack 2 packed bf16 (one u32) -> f32x2 {elem0, elem1}; 2 VALU ops
__device__ __forceinline__ f32x2 unpk(unsigned int u) {
    union { unsigned int u; float f; } lo, hi;
    lo.u = u << 16;
    hi.u = u & 0xffff0000u;
    return f32x2{lo.f, hi.f};
}

// packed fma -> v_pk_fma_f32 (VOP3P, gfx90a+); 1 issue for 2 lanes of math
__device__ __forceinline__ f32x2 pk_fma(f32x2 a, f32x2 b, f32x2 c) {
#if __has_builtin(__builtin_elementwise_fma)
    return __builtin_elementwise_fma(a, b, c);
#else
    return f32x2{fmaf(a.x, b.x, c.x), fmaf(a.y, b.y, c.y)};
#endif
}

// async 16B/lane global->LDS copy; lds base wave-uniform, lane i -> base+i*16
__device__ __forceinline__ void async16(const unsigned short* g, unsigned short* l) {
    __builtin_amdgcn_global_load_lds(
        (const __attribute__((address_space(1))) unsigned int*)g,
        (__attribute__((address_space(3))) unsigned int*)l, 16, 0, 0);
}

// ---------------------------------------------------------------------------
// prep: cast x to bf16 (8 elems/thread, vectorized) + cast+transpose weights
// to [N][K] bf16. R2: LDS-tiled 64x64 transpose — coalesced float4 reads
// along N, coalesced ushort4 writes along K (old path: 1 f32/lane @ 3KB
// stride = ~16x read amplification).
// ---------------------------------------------------------------------------
#define XCAST_BLOCKS 1568    // NTOK*256/8/256

__device__ __forceinline__ void transpose_tile(
    const float* __restrict__ src, unsigned short* __restrict__ dst,
    int K, int N, int kt, int nt, int tid, float* lds /*64x65*/)
{
    const int k0 = kt * 64, n0 = nt * 64;
    #pragma unroll
    for (int p = 0; p < 4; ++p) {               // read 16 k-rows x 64 n each
        const int r  = p * 16 + (tid >> 4);
        const int c4 = (tid & 15) * 4;
        const float4 v = *(const float4*)(src + (size_t)(k0 + r) * N + n0 + c4);
        lds[r * 65 + c4 + 0] = v.x; lds[r * 65 + c4 + 1] = v.y;
        lds[r * 65 + c4 + 2] = v.z; lds[r * 65 + c4 + 3] = v.w;
    }
    __syncthreads();
    #pragma unroll
    for (int p = 0; p < 4; ++p) {               // write 16 n-rows x 64 k each
        const int c  = p * 16 + (tid >> 4);
        const int k4 = (tid & 15) * 4;
        ushort4 o;
        o.x = f2b(lds[(k4 + 0) * 65 + c]);
        o.y = f2b(lds[(k4 + 1) * 65 + c]);
        o.z = f2b(lds[(k4 + 2) * 65 + c]);
        o.w = f2b(lds[(k4 + 3) * 65 + c]);
        *(ushort4*)(dst + (size_t)(n0 + c) * K + k0 + k4) = o;
    }
}

__global__ __launch_bounds__(256)
void prep_kernel(const float* __restrict__ x,
                 const float* __restrict__ Wq, const float* __restrict__ Wp,
                 const float* __restrict__ W1, const float* __restrict__ W2,
                 unsigned short* __restrict__ xb,
                 unsigned short* __restrict__ Wqb, unsigned short* __restrict__ Wpb,
                 unsigned short* __restrict__ W1b, unsigned short* __restrict__ W2b)
{
    __shared__ float lds[64 * 65];
    const int tid = threadIdx.x;
    if (blockIdx.x < XCAST_BLOCKS) {
        const int i = blockIdx.x * 256 + tid;   // 8 floats each
        const float4* xp = (const float4*)x + (size_t)i * 2;
        const float4 a = xp[0], b = xp[1];
        s16x8 o;
        o[0] = (short)f2b(a.x); o[1] = (short)f2b(a.y);
        o[2] = (short)f2b(a.z); o[3] = (short)f2b(a.w);
        o[4] = (short)f2b(b.x); o[5] = (short)f2b(b.y);
        o[6] = (short)f2b(b.z); o[7] = (short)f2b(b.w);
        *((s16x8*)xb + i) = o;
        return;
    }
    int wb = blockIdx.x - XCAST_BLOCKS;
    if (wb < 48) {                 // W_qkv: K=256, N=768 -> 4x12 tiles
        transpose_tile(Wq, Wqb, 256, 768, wb & 3, wb >> 2, tid, lds);
    } else if ((wb -= 48) < 16) {  // W_proj: K=256, N=256 -> 4x4
        transpose_tile(Wp, Wpb, 256, 256, wb & 3, wb >> 2, tid, lds);
    } else if ((wb -= 16) < 64) {  // W1: K=256, N=1024 -> 4x16
        transpose_tile(W1, W1b, 256, 1024, wb & 3, wb >> 2, tid, lds);
    } else {                       // W2: K=1024, N=256 -> 16x4
        wb -= 64;
        transpose_tile(W2, W2b, 1024, 256, wb & 15, wb >> 4, tid, lds);
    }
}

// ---------------------------------------------------------------------------
// bf16 MFMA GEMM, 128xBN tile (BN=128), 4 waves, 2-phase double-buffer (R1).
// A: bf16 [M][K], B: bf16 [N][K], both via global_load_lds.
// ---------------------------------------------------------------------------
template<int BN>
__global__ __launch_bounds__(256)
void gemm_k(const unsigned short* __restrict__ Ab,
            const unsigned short* __restrict__ Bt, const float* __restrict__ bias,
            float* __restrict__ outf, unsigned short* __restrict__ outb,
            int M, int N, int K, int relu)
{
    constexpr int NB  = BN / 32;
    constexpr int BPW = BN / 32;
    __shared__ unsigned short As[2][128 * 64];
    __shared__ unsigned short Bs[2][BN * 64];

    const int tid = threadIdx.x;
    const int bm = blockIdx.y * 128, bn = blockIdx.x * BN;
    const int wid = tid >> 6, lane = tid & 63;
    const int wm = (wid >> 1) * 64, wn = (wid & 1) * (BN / 2);
    const int row16 = lane & 15, quad = lane >> 4;
    const int crow = lane >> 3, ck8 = (lane & 7) * 8;

    f32x4 acc[4][NB] = {};

    auto stage = [&](int buf, int k0) {
        #pragma unroll
        for (int c = 0; c < 4; ++c) {
            const int ch = wid * 4 + c;
            async16(Ab + (size_t)(bm + ch * 8 + crow) * K + k0 + ck8, As[buf] + ch * 512);
        }
        #pragma unroll
        for (int c = 0; c < BPW; ++c) {
            const int ch = wid * BPW + c;
            async16(Bt + (size_t)(bn + ch * 8 + crow) * K + k0 + ck8, Bs[buf] + ch * 512);
        }
    };
    auto compute = [&](int buf) {
        #pragma unroll
        for (int kc = 0; kc < 2; ++kc) {
            s16x8 af[4], bf[NB];
            #pragma unroll
            for (int i = 0; i < 4; ++i)
                af[i] = *(const s16x8*)(As[buf] + (wm + i * 16 + row16) * 64 + kc * 32 + quad * 8);
            #pragma unroll
            for (int j = 0; j < NB; ++j)
                bf[j] = *(const s16x8*)(Bs[buf] + (wn + j * 16 + row16) * 64 + kc * 32 + quad * 8);
            #pragma unroll
            for (int i = 0; i < 4; ++i)
                #pragma unroll
                for (int j = 0; j < NB; ++j)
                    acc[i][j] = __builtin_amdgcn_mfma_f32_16x16x32_bf16(af[i], bf[j], acc[i][j], 0, 0, 0);
        }
    };

    stage(0, 0);
    __syncthreads();
    for (int k0 = 0; k0 < K; k0 += 128) {      // K % 128 == 0 (256 / 1024)
        stage(1, k0 + 64);
        compute(0);
        __syncthreads();
        if (k0 + 128 < K) stage(0, k0 + 128);
        compute(1);
        __syncthreads();
    }

    #pragma unroll
    for (int j = 0; j < NB; ++j) {
        const int col = bn + wn + j * 16 + row16;
        const float bb = bias[col];
        #pragma unroll
        for (int i = 0; i < 4; ++i) {
            const int r0 = bm + wm + i * 16 + quad * 4;
            #pragma unroll
            for (int reg = 0; reg < 4; ++reg) {
                float v = acc[i][j][reg] + bb;
                if (relu) v = fmaxf(v, 0.f);
                if (outf) outf[(size_t)(r0 + reg) * N + col] = v;
                if (outb) outb[(size_t)(r0 + reg) * N + col] = f2b(v);
            }
        }
    }
}

// ---------------------------------------------------------------------------
// Fused GEMM (N=256 full-row tile) + residual add + LayerNorm.
// out = LN(resid + A@Bt^T + bias) * g + beta.
// R2: BM=64, 512 threads (8 waves, 2m x 4n). Halves the per-block B-panel
// re-staging vs BM=32 (ffn2: 226 -> 113 MB total staged) and doubles
// resident waves/CU (8 -> 16). LDS 80 KB -> 2 blocks/CU.
// ---------------------------------------------------------------------------
__global__ __launch_bounds__(512)
void gemm_ln(const unsigned short* __restrict__ Ab, const unsigned short* __restrict__ Bt,
             const float* __restrict__ bias, const float* __restrict__ resid,
             const float* __restrict__ g, const float* __restrict__ beta,
             float* __restrict__ outf, unsigned short* __restrict__ outb, int K)
{
    __shared__ unsigned short As[2][64 * 64];    // 16 KB (buf0 reused for LN reduce)
    __shared__ unsigned short Bs[2][256 * 64];   // 64 KB

    const int tid = threadIdx.x;
    const int bm = blockIdx.x * 64;
    const int wid = tid >> 6, lane = tid & 63;
    const int wm = (wid >> 2) * 32, wn = (wid & 3) * 64;
    const int wc = wid & 3;
    const int row16 = lane & 15, quad = lane >> 4;
    const int crow = lane >> 3, ck8 = (lane & 7) * 8;

    f32x4 acc[2][4] = {};

    auto stage = [&](int buf, int k0) {
        // 40 chunks: 8 A (64 rows) + 32 B (256 rows); 5 per wave
        #pragma unroll
        for (int c = 0; c < 5; ++c) {
            const int ch = wid * 5 + c;
            if (ch < 8) {
                async16(Ab + (size_t)(bm + ch * 8 + crow) * K + k0 + ck8, As[buf] + ch * 512);
            } else {
                const int bc = ch - 8;
                async16(Bt + (size_t)(bc * 8 + crow) * K + k0 + ck8, Bs[buf] + bc * 512);
            }
        }
    };
    auto compute = [&](int buf) {
        #pragma unroll
        for (int kc = 0; kc < 2; ++kc) {
            s16x8 af[2], bf[4];
            #pragma unroll
            for (int i = 0; i < 2; ++i)
                af[i] = *(const s16x8*)(As[buf] + (wm + i * 16 + row16) * 64 + kc * 32 + quad * 8);
            #pragma unroll
            for (int j = 0; j < 4; ++j)
                bf[j] = *(const s16x8*)(Bs[buf] + (wn + j * 16 + row16) * 64 + kc * 32 + quad * 8);
            #pragma unroll
            for (int i = 0; i < 2; ++i)
                #pragma unroll
                for (int j = 0; j < 4; ++j)
                    acc[i][j] = __builtin_amdgcn_mfma_f32_16x16x32_bf16(af[i], bf[j], acc[i][j], 0, 0, 0);
        }
    };

    stage(0, 0);
    __syncthreads();
    for (int k0 = 0; k0 < K; k0 += 128) {      // K % 128 == 0 (256 / 1024)
        stage(1, k0 + 64);
        compute(0);
        __syncthreads();
        if (k0 + 128 < K) stage(0, k0 + 128);
        compute(1);
        __syncthreads();
    }

    // ---- epilogue: bias + residual, in-register
    float bb[4], gv[4], bev[4];
    #pragma unroll
    for (int j = 0; j < 4; ++j) {
        const int col = wn + j * 16 + row16;
        bb[j] = bias[col]; gv[j] = g[col]; bev[j] = beta[col];
    }
    #pragma unroll
    for (int i = 0; i < 2; ++i) {
        #pragma unroll
        for (int reg = 0; reg < 4; ++reg) {
            const size_t rb = (size_t)(bm + wm + i * 16 + quad * 4 + reg) * 256;
            #pragma unroll
            for (int j = 0; j < 4; ++j)
                acc[i][j][reg] += bb[j] + resid[rb + wn + j * 16 + row16];
        }
    }

    // ---- per-row sum / sumsq: reduce across row16 (16 lanes), then LDS
    float* red = (float*)As[0];           // [64 rows][4 col-waves][2]
    #pragma unroll
    for (int i = 0; i < 2; ++i) {
        #pragma unroll
        for (int reg = 0; reg < 4; ++reg) {
            float s1 = 0.f, s2 = 0.f;
            #pragma unroll
            for (int j = 0; j < 4; ++j) {
                const float t = acc[i][j][reg];
                s1 += t; s2 += t * t;
            }
            #pragma unroll
            for (int o = 1; o < 16; o <<= 1) {
                s1 += __shfl_xor(s1, o, 64);
                s2 += __shfl_xor(s2, o, 64);
            }
            if (row16 == 0) {
                const int lrow = wm + i * 16 + quad * 4 + reg;
                red[lrow * 8 + wc * 2]     = s1;
                red[lrow * 8 + wc * 2 + 1] = s2;
            }
        }
    }
    __syncthreads();
    float* stats = red + 512;             // [64][2] = m, invstd
    if (tid < 64) {
        const float S1 = red[tid*8] + red[tid*8+2] + red[tid*8+4] + red[tid*8+6];
        const float S2 = red[tid*8+1] + red[tid*8+3] + red[tid*8+5] + red[tid*8+7];
        const float m = S1 * (1.0f / 256.0f);
        const float var = S2 * (1.0f / 256.0f) - m * m;
        stats[tid * 2]     = m;
        stats[tid * 2 + 1] = rsqrtf(var + 1e-5f);
    }
    __syncthreads();

    // ---- normalize + store
    #pragma unroll
    for (int i = 0; i < 2; ++i) {
        #pragma unroll
        for (int reg = 0; reg < 4; ++reg) {
            const int lrow = wm + i * 16 + quad * 4 + reg;
            const float m = stats[lrow * 2], r = stats[lrow * 2 + 1];
            const size_t rb = (size_t)(bm + lrow) * 256;
            #pragma unroll
            for (int j = 0; j < 4; ++j) {
                const int col = wn + j * 16 + row16;
                const float o = (acc[i][j][reg] - m) * r * gv[j] + bev[j];
                outf[rb + col] = o;
                if (outb) outb[rb + col] = f2b(o);
            }
        }
    }
}

// ---------------------------------------------------------------------------
// Tiled neighborhood attention: block = (16x16 tile, head), 256 threads,
// 1 query/lane; K,V halo in LDS (pad 40, 16B-aligned rows); fused no-max
// softmax; packed bf16 unpack + v_pk_fma_f32 (R0).
// ---------------------------------------------------------------------------
__global__ __launch_bounds__(256, 2)
void natt_kernel(const unsigned short* __restrict__ qkvb, unsigned short* __restrict__ att)
{
    const int blk  = blockIdx.x;          // 4*16*8 = 512
    const int head = blk & 7;
    const int t2   = blk >> 3;
    const int tile = t2 & 15;
    const int b    = t2 >> 4;
    const int r0 = (tile >> 2) * 16, c0 = (tile & 3) * 16;
    const int hs = min(max(r0 - 3, 0), 34);
    const int ws = min(max(c0 - 3, 0), 34);

    __shared__ unsigned short Ks[NHTOK * KV_PAD];
    __shared__ unsigned short Vs[NHTOK * KV_PAD];

    const int tid = threadIdx.x;

    #pragma unroll
    for (int it = 0; it < 8; ++it) {
        const int t = it * 64 + (tid >> 2);
        if (t < NHTOK) {
            const int hr = t / HALO, hc = t - hr * HALO;
            const size_t rb = ((size_t)((b * 56 + hs + hr) * 56 + (ws + hc))) * 768;
            const int d8 = (tid & 3) * 8;
            *(s16x8*)(Ks + t * KV_PAD + d8) = *(const s16x8*)(qkvb + rb + 256 + head * 32 + d8);
            *(s16x8*)(Vs + t * KV_PAD + d8) = *(const s16x8*)(qkvb + rb + 512 + head * 32 + d8);
        }
    }

    const int qh = min(r0 + (tid >> 4), 55);
    const int qw = min(c0 + (tid & 15), 55);
    const int tok = (b * 56 + qh) * 56 + qw;
    const int ro = min(max(qh - 3, 0), 49) - hs;
    const int co = min(max(qw - 3, 0), 49) - ws;

    f32x2 qf[16];
    {
        const unsigned int* qp = (const unsigned int*)(qkvb + (size_t)tok * 768 + head * 32);
        #pragma unroll
        for (int p = 0; p < 16; ++p)
            qf[p] = unpk(qp[p]) * 0.17677669529663687f;
    }
    __syncthreads();

    f32x2 acc[16] = {};
    float sum = 0.f;
    for (int i = 0; i < 7; ++i) {
        const int trow = (ro + i) * HALO + co;
        #pragma unroll
        for (int j = 0; j < 7; ++j) {
            const unsigned int* kp = (const unsigned int*)(Ks + (trow + j) * KV_PAD);
            const unsigned int* vp = (const unsigned int*)(Vs + (trow + j) * KV_PAD);
            const uint4 ka = *(const uint4*)(kp);
            const uint4 kb = *(const uint4*)(kp + 4);
            const uint4 kc = *(const uint4*)(kp + 8);
            const uint4 kd = *(const uint4*)(kp + 12);
            const uint4 va = *(const uint4*)(vp);
            const uint4 vb = *(const uint4*)(vp + 4);
            const uint4 vc = *(const uint4*)(vp + 8);
            const uint4 vd = *(const uint4*)(vp + 12);
            // QK dot: 16 pk_fma, two parallel chains (8 deep each)
            f32x2 sa = {0.f, 0.f}, sb = {0.f, 0.f};
            sa = pk_fma(qf[0],  unpk(ka.x), sa);  sb = pk_fma(qf[1],  unpk(ka.y), sb);
            sa = pk_fma(qf[2],  unpk(ka.z), sa);  sb = pk_fma(qf[3],  unpk(ka.w), sb);
            sa = pk_fma(qf[4],  unpk(kb.x), sa);  sb = pk_fma(qf[5],  unpk(kb.y), sb);
            sa = pk_fma(qf[6],  unpk(kb.z), sa);  sb = pk_fma(qf[7],  unpk(kb.w), sb);
            sa = pk_fma(qf[8],  unpk(kc.x), sa);  sb = pk_fma(qf[9],  unpk(kc.y), sb);
            sa = pk_fma(qf[10], unpk(kc.z), sa);  sb = pk_fma(qf[11], unpk(kc.w), sb);
            sa = pk_fma(qf[12], unpk(kd.x), sa);  sb = pk_fma(qf[13], unpk(kd.y), sb);
            sa = pk_fma(qf[14], unpk(kd.z), sa);  sb = pk_fma(qf[15], unpk(kd.w), sb);
            const float p = __expf(sa.x + sa.y + sb.x + sb.y);
            sum += p;
            const f32x2 pv = {p, p};
            acc[0]  = pk_fma(pv, unpk(va.x), acc[0]);
            acc[1]  = pk_fma(pv, unpk(va.y), acc[1]);
            acc[2]  = pk_fma(pv, unpk(va.z), acc[2]);
            acc[3]  = pk_fma(pv, unpk(va.w), acc[3]);
            acc[4]  = pk_fma(pv, unpk(vb.x), acc[4]);
            acc[5]  = pk_fma(pv, unpk(vb.y), acc[5]);
            acc[6]  = pk_fma(pv, unpk(vb.z), acc[6]);
            acc[7]  = pk_fma(pv, unpk(vb.w), acc[7]);
            acc[8]  = pk_fma(pv, unpk(vc.x), acc[8]);
            acc[9]  = pk_fma(pv, unpk(vc.y), acc[9]);
            acc[10] = pk_fma(pv, unpk(vc.z), acc[10]);
            acc[11] = pk_fma(pv, unpk(vc.w), acc[11]);
            acc[12] = pk_fma(pv, unpk(vd.x), acc[12]);
            acc[13] = pk_fma(pv, unpk(vd.y), acc[13]);
            acc[14] = pk_fma(pv, unpk(vd.z), acc[14]);
            acc[15] = pk_fma(pv, unpk(vd.w), acc[15]);
        }
    }
    const float inv = 1.0f / sum;

    unsigned short* op = att + (size_t)tok * DMODEL + head * 32;
    #pragma unroll
    for (int d4 = 0; d4 < 8; ++d4) {
        ushort4 o;
        o.x = f2b(acc[d4 * 2].x     * inv);
        o.y = f2b(acc[d4 * 2].y     * inv);
        o.z = f2b(acc[d4 * 2 + 1].x * inv);
        o.w = f2b(acc[d4 * 2 + 1].y * inv);
        *(ushort4*)(op + d4 * 4) = o;
    }
}

// ---------------------------------------------------------------------------
extern "C" void kernel_launch(void* const* d_in, const int* in_sizes, int n_in,
                              void* d_out, int out_size, void* d_ws, size_t ws_size,
                              hipStream_t stream)
{
    const float* x      = (const float*)d_in[0];
    const float* W_qkv  = (const float*)d_in[1];
    const float* b_qkv  = (const float*)d_in[2];
    const float* W_proj = (const float*)d_in[3];
    const float* b_proj = (const float*)d_in[4];
    const float* W1     = (const float*)d_in[5];
    const float* b1     = (const float*)d_in[6];
    const float* W2     = (const float*)d_in[7];
    const float* b2     = (const float*)d_in[8];
    const float* g1     = (const float*)d_in[9];
    const float* be1    = (const float*)d_in[10];
    const float* g2     = (const float*)d_in[11];
    const float* be2    = (const float*)d_in[12];
    float* out = (float*)d_out;

    char* ws = (char*)d_ws;
    const int M = NTOK;  // 12544

    unsigned short* qkvb = (unsigned short*)ws;                     // [M][768] bf16
    unsigned short* h    = (unsigned short*)ws;                     // [M][1024] bf16 (after qkvb dead)
    unsigned short* attb = (unsigned short*)(ws + 38535168);        // [M][256] bf16
    float*          xn   = (float*)(ws + 57802752);                 // [M][256] f32
    unsigned short* xnb  = (unsigned short*)(ws + 70647808);        // [M][256] bf16
    unsigned short* Wqb  = (unsigned short*)(ws + 77070336);
    unsigned short* Wpb  = Wqb + 196608;
    unsigned short* W1b  = Wpb + 65536;
    unsigned short* W2b  = W1b + 262144;
    unsigned short* xb   = (unsigned short*)(ws + 78643200);        // [M][256] bf16

    dim3 blk(256);

    // 0) cast x to bf16 + cast/transpose weights to bf16 (tiled transpose)
    prep_kernel<<<dim3(XCAST_BLOCKS + 48 + 16 + 64 + 64), blk, 0, stream>>>(
        x, W_qkv, W_proj, W1, W2, xb, Wqb, Wpb, W1b, W2b);

    // 1) qkvb = bf16(xb @ W_qkv + b_qkv)
    gemm_k<128><<<dim3(6, 98), blk, 0, stream>>>(xb, Wqb, b_qkv, nullptr, qkvb, M, 768, 256, 0);

    // 2) tiled neighborhood attention -> attb
    natt_kernel<<<dim3(512), blk, 0, stream>>>(qkvb, attb);

    // 3+4) xn = LN(x + attb @ W_proj + b_proj)  (f32 + bf16), fused
    gemm_ln<<<dim3(M / 64), dim3(512), 0, stream>>>(attb, Wpb, b_proj, x, g1, be1, xn, xnb, 256);

    // 5) h = relu(xnb @ W1 + b1)  (bf16)
    gemm_k<128><<<dim3(8, 98), blk, 0, stream>>>(xnb, W1b, b1, nullptr, h, M, 1024, 256, 1);

    // 6+7) out = LN(xn + h @ W2 + b2), fused
    gemm_ln<<<dim3(M / 64), dim3(512), 0, stream>>>(h, W2b, b2, xn, g2, be2, out, nullptr, 1024);
}

// Round 4
// 178.327 us; speedup vs baseline: 1.1738x; 1.0925x over previous
//
#include <hip/hip_runtime.h>
#include <math.h>

// Problem constants
#define BATCH 4
#define HH 56
#define WW 56
#define DMODEL 256
#define NHEADS 8
#define HD 32
#define NNB 49               // 7x7 neighborhood
#define NTOK (BATCH*HH*WW)   // 12544

#define HALO 22              // 16 + 2*3
#define NHTOK (HALO*HALO)    // 484
// KV_PAD must keep rows 16B-aligned for ds_*_b128: stride (bf16) must be a
// multiple of 8. 40 (80B) aligned & proven; 36 broke b128 codegen (R9, 3.5x).
#define KV_PAD 40

typedef __attribute__((ext_vector_type(8))) short s16x8;
typedef __attribute__((ext_vector_type(4))) float f32x4;
typedef __attribute__((ext_vector_type(2))) float f32x2;

__device__ inline unsigned short f2b(float f) {
    union { float f; unsigned int u; } v; v.f = f;
    unsigned int r = v.u + 0x7FFF + ((v.u >> 16) & 1);  // RNE
    return (unsigned short)(r >> 16);
}
__device__ inline float b2f(unsigned short u) {
    union { float f; unsigned int u; } v; v.u = ((unsigned int)u) << 16;
    return v.f;
}

// unpack 2 packed bf16 (one u32) -> f32x2 {elem0, elem1}; 2 VALU ops
__device__ __forceinline__ f32x2 unpk(unsigned int u) {
    union { unsigned int u; float f; } lo, hi;
    lo.u = u << 16;
    hi.u = u & 0xffff0000u;
    return f32x2{lo.f, hi.f};
}

// packed fma -> v_pk_fma_f32 (VOP3P, gfx90a+); 1 issue for 2 lanes of math
__device__ __forceinline__ f32x2 pk_fma(f32x2 a, f32x2 b, f32x2 c) {
#if __has_builtin(__builtin_elementwise_fma)
    return __builtin_elementwise_fma(a, b, c);
#else
    return f32x2{fmaf(a.x, b.x, c.x), fmaf(a.y, b.y, c.y)};
#endif
}

// async 16B/lane global->LDS copy; lds base wave-uniform, lane i -> base+i*16
__device__ __forceinline__ void async16(const unsigned short* g, unsigned short* l) {
    __builtin_amdgcn_global_load_lds(
        (const __attribute__((address_space(1))) unsigned int*)g,
        (__attribute__((address_space(3))) unsigned int*)l, 16, 0, 0);
}

// ---------------------------------------------------------------------------
// prep: cast x to bf16 (8 elems/thread, vectorized) + cast+transpose weights
// to [N][K] bf16 via LDS-tiled 64x64 transpose (R2).
// ---------------------------------------------------------------------------
#define XCAST_BLOCKS 1568    // NTOK*256/8/256

__device__ __forceinline__ void transpose_tile(
    const float* __restrict__ src, unsigned short* __restrict__ dst,
    int K, int N, int kt, int nt, int tid, float* lds /*64x65*/)
{
    const int k0 = kt * 64, n0 = nt * 64;
    #pragma unroll
    for (int p = 0; p < 4; ++p) {               // read 16 k-rows x 64 n each
        const int r  = p * 16 + (tid >> 4);
        const int c4 = (tid & 15) * 4;
        const float4 v = *(const float4*)(src + (size_t)(k0 + r) * N + n0 + c4);
        lds[r * 65 + c4 + 0] = v.x; lds[r * 65 + c4 + 1] = v.y;
        lds[r * 65 + c4 + 2] = v.z; lds[r * 65 + c4 + 3] = v.w;
    }
    __syncthreads();
    #pragma unroll
    for (int p = 0; p < 4; ++p) {               // write 16 n-rows x 64 k each
        const int c  = p * 16 + (tid >> 4);
        const int k4 = (tid & 15) * 4;
        ushort4 o;
        o.x = f2b(lds[(k4 + 0) * 65 + c]);
        o.y = f2b(lds[(k4 + 1) * 65 + c]);
        o.z = f2b(lds[(k4 + 2) * 65 + c]);
        o.w = f2b(lds[(k4 + 3) * 65 + c]);
        *(ushort4*)(dst + (size_t)(n0 + c) * K + k0 + k4) = o;
    }
}

__global__ __launch_bounds__(256)
void prep_kernel(const float* __restrict__ x,
                 const float* __restrict__ Wq, const float* __restrict__ Wp,
                 const float* __restrict__ W1, const float* __restrict__ W2,
                 unsigned short* __restrict__ xb,
                 unsigned short* __restrict__ Wqb, unsigned short* __restrict__ Wpb,
                 unsigned short* __restrict__ W1b, unsigned short* __restrict__ W2b)
{
    __shared__ float lds[64 * 65];
    const int tid = threadIdx.x;
    if (blockIdx.x < XCAST_BLOCKS) {
        const int i = blockIdx.x * 256 + tid;   // 8 floats each
        const float4* xp = (const float4*)x + (size_t)i * 2;
        const float4 a = xp[0], b = xp[1];
        s16x8 o;
        o[0] = (short)f2b(a.x); o[1] = (short)f2b(a.y);
        o[2] = (short)f2b(a.z); o[3] = (short)f2b(a.w);
        o[4] = (short)f2b(b.x); o[5] = (short)f2b(b.y);
        o[6] = (short)f2b(b.z); o[7] = (short)f2b(b.w);
        *((s16x8*)xb + i) = o;
        return;
    }
    int wb = blockIdx.x - XCAST_BLOCKS;
    if (wb < 48) {                 // W_qkv: K=256, N=768 -> 4x12 tiles
        transpose_tile(Wq, Wqb, 256, 768, wb & 3, wb >> 2, tid, lds);
    } else if ((wb -= 48) < 16) {  // W_proj: K=256, N=256 -> 4x4
        transpose_tile(Wp, Wpb, 256, 256, wb & 3, wb >> 2, tid, lds);
    } else if ((wb -= 16) < 64) {  // W1: K=256, N=1024 -> 4x16
        transpose_tile(W1, W1b, 256, 1024, wb & 3, wb >> 2, tid, lds);
    } else {                       // W2: K=1024, N=256 -> 16x4
        wb -= 64;
        transpose_tile(W2, W2b, 1024, 256, wb & 15, wb >> 4, tid, lds);
    }
}

// ---------------------------------------------------------------------------
// bf16 MFMA GEMM, 128x128 tile, 4 waves, 2-phase double-buffer (R1).
// R4: (1) T2 XOR-swizzle via pre-swizzled GLOBAL source (LDS dest stays
//     lane-linear per rule #21); fragment reads XOR the same way ->
//     16-way bank conflict becomes 2-way (free).
// (2) bijective XCD chunking (m204) on flattened bm-major grid: each XCD
//     owns a contiguous bm range -> A-panels fetched ~once device-wide.
// (3) LDS-bounce epilogue: acc -> bf16 into dead As buffer, then fully
//     coalesced 16B stores (kills the 1.65x write amplification).
// Output is always bf16 here (qkv, ffn1-h).
// ---------------------------------------------------------------------------
__global__ __launch_bounds__(256)
void gemm_k(const unsigned short* __restrict__ Ab,
            const unsigned short* __restrict__ Bt, const float* __restrict__ bias,
            unsigned short* __restrict__ outb,
            int N, int K, int relu)
{
    __shared__ unsigned short As[2][128 * 64];   // 32 KB (reused as Cs in epilogue)
    __shared__ unsigned short Bs[2][128 * 64];   // 32 KB

    const int tid = threadIdx.x;

    // m204 bijective XCD chunk swizzle; desired ordering d is bm-major.
    const int nwg = gridDim.x;
    const int q8 = nwg >> 3, r8 = nwg & 7;
    const int xcd = blockIdx.x & 7, pos = blockIdx.x >> 3;
    const int d = (xcd < r8 ? xcd * (q8 + 1) : r8 * (q8 + 1) + (xcd - r8) * q8) + pos;
    const int nbx = N >> 7;                      // 128-wide col tiles
    const int bm = (d / nbx) * 128, bn = (d % nbx) * 128;

    const int wid = tid >> 6, lane = tid & 63;
    const int wm = (wid >> 1) * 64, wn = (wid & 1) * 64;
    const int row16 = lane & 15, quad = lane >> 4;
    const int crow = lane >> 3;
    const int ckS = ((lane & 7) ^ crow) * 8;     // XOR-swizzled source k-block

    f32x4 acc[4][4] = {};

    auto stage = [&](int buf, int k0) {
        #pragma unroll
        for (int c = 0; c < 4; ++c) {
            const int ch = wid * 4 + c;
            async16(Ab + (size_t)(bm + ch * 8 + crow) * K + k0 + ckS, As[buf] + ch * 512);
        }
        #pragma unroll
        for (int c = 0; c < 4; ++c) {
            const int ch = wid * 4 + c;
            async16(Bt + (size_t)(bn + ch * 8 + crow) * K + k0 + ckS, Bs[buf] + ch * 512);
        }
    };
    auto compute = [&](int buf) {
        #pragma unroll
        for (int kc = 0; kc < 2; ++kc) {
            s16x8 af[4], bf[4];
            #pragma unroll
            for (int i = 0; i < 4; ++i)
                af[i] = *(const s16x8*)(As[buf] + (wm + i * 16 + row16) * 64
                                        + (((kc * 4 + quad) ^ (row16 & 7)) * 8));
            #pragma unroll
            for (int j = 0; j < 4; ++j)
                bf[j] = *(const s16x8*)(Bs[buf] + (wn + j * 16 + row16) * 64
                                        + (((kc * 4 + quad) ^ (row16 & 7)) * 8));
            #pragma unroll
            for (int i = 0; i < 4; ++i)
                #pragma unroll
                for (int j = 0; j < 4; ++j)
                    acc[i][j] = __builtin_amdgcn_mfma_f32_16x16x32_bf16(af[i], bf[j], acc[i][j], 0, 0, 0);
        }
    };

    stage(0, 0);
    __syncthreads();
    for (int k0 = 0; k0 < K; k0 += 128) {      // K % 128 == 0 (256)
        stage(1, k0 + 64);
        compute(0);
        __syncthreads();
        if (k0 + 128 < K) stage(0, k0 + 128);
        compute(1);
        __syncthreads();
    }

    // ---- epilogue: bias (+relu) -> bf16 via LDS bounce, coalesced stores
    unsigned short* Cs = (unsigned short*)As;    // 128x128 bf16 = 32 KB
    #pragma unroll
    for (int j = 0; j < 4; ++j) {
        const int col = wn + j * 16 + row16;
        const float bb = bias[bn + col];
        #pragma unroll
        for (int i = 0; i < 4; ++i) {
            const int rr = wm + i * 16 + quad * 4;
            #pragma unroll
            for (int reg = 0; reg < 4; ++reg) {
                float v = acc[i][j][reg] + bb;
                if (relu) v = fmaxf(v, 0.f);
                Cs[(rr + reg) * 128 + col] = f2b(v);
            }
        }
    }
    __syncthreads();
    #pragma unroll
    for (int p = 0; p < 8; ++p) {
        const int s = p * 256 + tid;             // 2048 x 16B chunks
        const int rr = s >> 4, cb = (s & 15) * 8;
        *(s16x8*)(outb + (size_t)(bm + rr) * N + bn + cb) = *(const s16x8*)(Cs + rr * 128 + cb);
    }
}

// ---------------------------------------------------------------------------
// Fused GEMM (N=256 full-row tile) + residual add + LayerNorm.
// out = LN(resid + A@Bt^T + bias) * g + beta.
// BM=64, 512 threads (8 waves, 2m x 4n) (R2). R4: T2 XOR-swizzle (same
// pre-swizzled-source scheme as gemm_k) on A and B staging/reads.
// ---------------------------------------------------------------------------
__global__ __launch_bounds__(512)
void gemm_ln(const unsigned short* __restrict__ Ab, const unsigned short* __restrict__ Bt,
             const float* __restrict__ bias, const float* __restrict__ resid,
             const float* __restrict__ g, const float* __restrict__ beta,
             float* __restrict__ outf, unsigned short* __restrict__ outb, int K)
{
    __shared__ unsigned short As[2][64 * 64];    // 16 KB (buf0 reused for LN reduce)
    __shared__ unsigned short Bs[2][256 * 64];   // 64 KB

    const int tid = threadIdx.x;
    const int bm = blockIdx.x * 64;
    const int wid = tid >> 6, lane = tid & 63;
    const int wm = (wid >> 2) * 32, wn = (wid & 3) * 64;
    const int wc = wid & 3;
    const int row16 = lane & 15, quad = lane >> 4;
    const int crow = lane >> 3;
    const int ckS = ((lane & 7) ^ crow) * 8;     // XOR-swizzled source k-block

    f32x4 acc[2][4] = {};

    auto stage = [&](int buf, int k0) {
        // 40 chunks: 8 A (64 rows) + 32 B (256 rows); 5 per wave
        #pragma unroll
        for (int c = 0; c < 5; ++c) {
            const int ch = wid * 5 + c;
            if (ch < 8) {
                async16(Ab + (size_t)(bm + ch * 8 + crow) * K + k0 + ckS, As[buf] + ch * 512);
            } else {
                const int bc = ch - 8;
                async16(Bt + (size_t)(bc * 8 + crow) * K + k0 + ckS, Bs[buf] + bc * 512);
            }
        }
    };
    auto compute = [&](int buf) {
        #pragma unroll
        for (int kc = 0; kc < 2; ++kc) {
            s16x8 af[2], bf[4];
            #pragma unroll
            for (int i = 0; i < 2; ++i)
                af[i] = *(const s16x8*)(As[buf] + (wm + i * 16 + row16) * 64
                                        + (((kc * 4 + quad) ^ (row16 & 7)) * 8));
            #pragma unroll
            for (int j = 0; j < 4; ++j)
                bf[j] = *(const s16x8*)(Bs[buf] + (wn + j * 16 + row16) * 64
                                        + (((kc * 4 + quad) ^ (row16 & 7)) * 8));
            #pragma unroll
            for (int i = 0; i < 2; ++i)
                #pragma unroll
                for (int j = 0; j < 4; ++j)
                    acc[i][j] = __builtin_amdgcn_mfma_f32_16x16x32_bf16(af[i], bf[j], acc[i][j], 0, 0, 0);
        }
    };

    stage(0, 0);
    __syncthreads();
    for (int k0 = 0; k0 < K; k0 += 128) {      // K % 128 == 0 (256 / 1024)
        stage(1, k0 + 64);
        compute(0);
        __syncthreads();
        if (k0 + 128 < K) stage(0, k0 + 128);
        compute(1);
        __syncthreads();
    }

    // ---- epilogue: bias + residual, in-register
    float bb[4], gv[4], bev[4];
    #pragma unroll
    for (int j = 0; j < 4; ++j) {
        const int col = wn + j * 16 + row16;
        bb[j] = bias[col]; gv[j] = g[col]; bev[j] = beta[col];
    }
    #pragma unroll
    for (int i = 0; i < 2; ++i) {
        #pragma unroll
        for (int reg = 0; reg < 4; ++reg) {
            const size_t rb = (size_t)(bm + wm + i * 16 + quad * 4 + reg) * 256;
            #pragma unroll
            for (int j = 0; j < 4; ++j)
                acc[i][j][reg] += bb[j] + resid[rb + wn + j * 16 + row16];
        }
    }

    // ---- per-row sum / sumsq: reduce across row16 (16 lanes), then LDS
    float* red = (float*)As[0];           // [64 rows][4 col-waves][2]
    #pragma unroll
    for (int i = 0; i < 2; ++i) {
        #pragma unroll
        for (int reg = 0; reg < 4; ++reg) {
            float s1 = 0.f, s2 = 0.f;
            #pragma unroll
            for (int j = 0; j < 4; ++j) {
                const float t = acc[i][j][reg];
                s1 += t; s2 += t * t;
            }
            #pragma unroll
            for (int o = 1; o < 16; o <<= 1) {
                s1 += __shfl_xor(s1, o, 64);
                s2 += __shfl_xor(s2, o, 64);
            }
            if (row16 == 0) {
                const int lrow = wm + i * 16 + quad * 4 + reg;
                red[lrow * 8 + wc * 2]     = s1;
                red[lrow * 8 + wc * 2 + 1] = s2;
            }
        }
    }
    __syncthreads();
    float* stats = red + 512;             // [64][2] = m, invstd
    if (tid < 64) {
        const float S1 = red[tid*8] + red[tid*8+2] + red[tid*8+4] + red[tid*8+6];
        const float S2 = red[tid*8+1] + red[tid*8+3] + red[tid*8+5] + red[tid*8+7];
        const float m = S1 * (1.0f / 256.0f);
        const float var = S2 * (1.0f / 256.0f) - m * m;
        stats[tid * 2]     = m;
        stats[tid * 2 + 1] = rsqrtf(var + 1e-5f);
    }
    __syncthreads();

    // ---- normalize + store
    #pragma unroll
    for (int i = 0; i < 2; ++i) {
        #pragma unroll
        for (int reg = 0; reg < 4; ++reg) {
            const int lrow = wm + i * 16 + quad * 4 + reg;
            const float m = stats[lrow * 2], r = stats[lrow * 2 + 1];
            const size_t rb = (size_t)(bm + lrow) * 256;
            #pragma unroll
            for (int j = 0; j < 4; ++j) {
                const int col = wn + j * 16 + row16;
                const float o = (acc[i][j][reg] - m) * r * gv[j] + bev[j];
                outf[rb + col] = o;
                if (outb) outb[rb + col] = f2b(o);
            }
        }
    }
}

// ---------------------------------------------------------------------------
// Tiled neighborhood attention: block = (16x16 tile, head), 256 threads,
// 1 query/lane; K,V halo in LDS (pad 40, 16B-aligned rows); fused no-max
// softmax; packed bf16 unpack + v_pk_fma_f32 (R0).
// ---------------------------------------------------------------------------
__global__ __launch_bounds__(256, 2)
void natt_kernel(const unsigned short* __restrict__ qkvb, unsigned short* __restrict__ att)
{
    const int blk  = blockIdx.x;          // 4*16*8 = 512
    const int head = blk & 7;
    const int t2   = blk >> 3;
    const int tile = t2 & 15;
    const int b    = t2 >> 4;
    const int r0 = (tile >> 2) * 16, c0 = (tile & 3) * 16;
    const int hs = min(max(r0 - 3, 0), 34);
    const int ws = min(max(c0 - 3, 0), 34);

    __shared__ unsigned short Ks[NHTOK * KV_PAD];
    __shared__ unsigned short Vs[NHTOK * KV_PAD];

    const int tid = threadIdx.x;

    #pragma unroll
    for (int it = 0; it < 8; ++it) {
        const int t = it * 64 + (tid >> 2);
        if (t < NHTOK) {
            const int hr = t / HALO, hc = t - hr * HALO;
            const size_t rb = ((size_t)((b * 56 + hs + hr) * 56 + (ws + hc))) * 768;
            const int d8 = (tid & 3) * 8;
            *(s16x8*)(Ks + t * KV_PAD + d8) = *(const s16x8*)(qkvb + rb + 256 + head * 32 + d8);
            *(s16x8*)(Vs + t * KV_PAD + d8) = *(const s16x8*)(qkvb + rb + 512 + head * 32 + d8);
        }
    }

    const int qh = min(r0 + (tid >> 4), 55);
    const int qw = min(c0 + (tid & 15), 55);
    const int tok = (b * 56 + qh) * 56 + qw;
    const int ro = min(max(qh - 3, 0), 49) - hs;
    const int co = min(max(qw - 3, 0), 49) - ws;

    f32x2 qf[16];
    {
        const unsigned int* qp = (const unsigned int*)(qkvb + (size_t)tok * 768 + head * 32);
        #pragma unroll
        for (int p = 0; p < 16; ++p)
            qf[p] = unpk(qp[p]) * 0.17677669529663687f;
    }
    __syncthreads();

    f32x2 acc[16] = {};
    float sum = 0.f;
    for (int i = 0; i < 7; ++i) {
        const int trow = (ro + i) * HALO + co;
        #pragma unroll
        for (int j = 0; j < 7; ++j) {
            const unsigned int* kp = (const unsigned int*)(Ks + (trow + j) * KV_PAD);
            const unsigned int* vp = (const unsigned int*)(Vs + (trow + j) * KV_PAD);
            const uint4 ka = *(const uint4*)(kp);
            const uint4 kb = *(const uint4*)(kp + 4);
            const uint4 kc = *(const uint4*)(kp + 8);
            const uint4 kd = *(const uint4*)(kp + 12);
            const uint4 va = *(const uint4*)(vp);
            const uint4 vb = *(const uint4*)(vp + 4);
            const uint4 vc = *(const uint4*)(vp + 8);
            const uint4 vd = *(const uint4*)(vp + 12);
            // QK dot: 16 pk_fma, two parallel chains (8 deep each)
            f32x2 sa = {0.f, 0.f}, sb = {0.f, 0.f};
            sa = pk_fma(qf[0],  unpk(ka.x), sa);  sb = pk_fma(qf[1],  unpk(ka.y), sb);
            sa = pk_fma(qf[2],  unpk(ka.z), sa);  sb = pk_fma(qf[3],  unpk(ka.w), sb);
            sa = pk_fma(qf[4],  unpk(kb.x), sa);  sb = pk_fma(qf[5],  unpk(kb.y), sb);
            sa = pk_fma(qf[6],  unpk(kb.z), sa);  sb = pk_fma(qf[7],  unpk(kb.w), sb);
            sa = pk_fma(qf[8],  unpk(kc.x), sa);  sb = pk_fma(qf[9],  unpk(kc.y), sb);
            sa = pk_fma(qf[10], unpk(kc.z), sa);  sb = pk_fma(qf[11], unpk(kc.w), sb);
            sa = pk_fma(qf[12], unpk(kd.x), sa);  sb = pk_fma(qf[13], unpk(kd.y), sb);
            sa = pk_fma(qf[14], unpk(kd.z), sa);  sb = pk_fma(qf[15], unpk(kd.w), sb);
            const float p = __expf(sa.x + sa.y + sb.x + sb.y);
            sum += p;
            const f32x2 pv = {p, p};
            acc[0]  = pk_fma(pv, unpk(va.x), acc[0]);
            acc[1]  = pk_fma(pv, unpk(va.y), acc[1]);
            acc[2]  = pk_fma(pv, unpk(va.z), acc[2]);
            acc[3]  = pk_fma(pv, unpk(va.w), acc[3]);
            acc[4]  = pk_fma(pv, unpk(vb.x), acc[4]);
            acc[5]  = pk_fma(pv, unpk(vb.y), acc[5]);
            acc[6]  = pk_fma(pv, unpk(vb.z), acc[6]);
            acc[7]  = pk_fma(pv, unpk(vb.w), acc[7]);
            acc[8]  = pk_fma(pv, unpk(vc.x), acc[8]);
            acc[9]  = pk_fma(pv, unpk(vc.y), acc[9]);
            acc[10] = pk_fma(pv, unpk(vc.z), acc[10]);
            acc[11] = pk_fma(pv, unpk(vc.w), acc[11]);
            acc[12] = pk_fma(pv, unpk(vd.x), acc[12]);
            acc[13] = pk_fma(pv, unpk(vd.y), acc[13]);
            acc[14] = pk_fma(pv, unpk(vd.z), acc[14]);
            acc[15] = pk_fma(pv, unpk(vd.w), acc[15]);
        }
    }
    const float inv = 1.0f / sum;

    unsigned short* op = att + (size_t)tok * DMODEL + head * 32;
    #pragma unroll
    for (int d4 = 0; d4 < 8; ++d4) {
        ushort4 o;
        o.x = f2b(acc[d4 * 2].x     * inv);
        o.y = f2b(acc[d4 * 2].y     * inv);
        o.z = f2b(acc[d4 * 2 + 1].x * inv);
        o.w = f2b(acc[d4 * 2 + 1].y * inv);
        *(ushort4*)(op + d4 * 4) = o;
    }
}

// ---------------------------------------------------------------------------
extern "C" void kernel_launch(void* const* d_in, const int* in_sizes, int n_in,
                              void* d_out, int out_size, void* d_ws, size_t ws_size,
                              hipStream_t stream)
{
    const float* x      = (const float*)d_in[0];
    const float* W_qkv  = (const float*)d_in[1];
    const float* b_qkv  = (const float*)d_in[2];
    const float* W_proj = (const float*)d_in[3];
    const float* b_proj = (const float*)d_in[4];
    const float* W1     = (const float*)d_in[5];
    const float* b1     = (const float*)d_in[6];
    const float* W2     = (const float*)d_in[7];
    const float* b2     = (const float*)d_in[8];
    const float* g1     = (const float*)d_in[9];
    const float* be1    = (const float*)d_in[10];
    const float* g2     = (const float*)d_in[11];
    const float* be2    = (const float*)d_in[12];
    float* out = (float*)d_out;

    char* ws = (char*)d_ws;
    const int M = NTOK;  // 12544

    unsigned short* qkvb = (unsigned short*)ws;                     // [M][768] bf16
    unsigned short* h    = (unsigned short*)ws;                     // [M][1024] bf16 (after qkvb dead)
    unsigned short* attb = (unsigned short*)(ws + 38535168);        // [M][256] bf16
    float*          xn   = (float*)(ws + 57802752);                 // [M][256] f32
    unsigned short* xnb  = (unsigned short*)(ws + 70647808);        // [M][256] bf16
    unsigned short* Wqb  = (unsigned short*)(ws + 77070336);
    unsigned short* Wpb  = Wqb + 196608;
    unsigned short* W1b  = Wpb + 65536;
    unsigned short* W2b  = W1b + 262144;
    unsigned short* xb   = (unsigned short*)(ws + 78643200);        // [M][256] bf16

    dim3 blk(256);

    // 0) cast x to bf16 + cast/transpose weights to bf16 (tiled transpose)
    prep_kernel<<<dim3(XCAST_BLOCKS + 48 + 16 + 64 + 64), blk, 0, stream>>>(
        x, W_qkv, W_proj, W1, W2, xb, Wqb, Wpb, W1b, W2b);

    // 1) qkvb = bf16(xb @ W_qkv + b_qkv)   (588 blocks, XCD-chunked)
    gemm_k<<<dim3(6 * 98), blk, 0, stream>>>(xb, Wqb, b_qkv, qkvb, 768, 256, 0);

    // 2) tiled neighborhood attention -> attb
    natt_kernel<<<dim3(512), blk, 0, stream>>>(qkvb, attb);

    // 3+4) xn = LN(x + attb @ W_proj + b_proj)  (f32 + bf16), fused
    gemm_ln<<<dim3(M / 64), dim3(512), 0, stream>>>(attb, Wpb, b_proj, x, g1, be1, xn, xnb, 256);

    // 5) h = relu(xnb @ W1 + b1)  (bf16, 784 blocks, XCD-chunked)
    gemm_k<<<dim3(8 * 98), blk, 0, stream>>>(xnb, W1b, b1, h, 1024, 256, 1);

    // 6+7) out = LN(xn + h @ W2 + b2), fused
    gemm_ln<<<dim3(M / 64), dim3(512), 0, stream>>>(h, W2b, b2, xn, g2, be2, out, nullptr, 1024);
}

// Round 5
// 174.106 us; speedup vs baseline: 1.2022x; 1.0242x over previous
//
#include <hip/hip_runtime.h>
#include <math.h>

// Problem constants
#define BATCH 4
#define HH 56
#define WW 56
#define DMODEL 256
#define NHEADS 8
#define HD 32
#define NNB 49               // 7x7 neighborhood
#define NTOK (BATCH*HH*WW)   // 12544

#define HALO 22              // 16 + 2*3
#define NHTOK (HALO*HALO)    // 484
#define KV_PAD 40

typedef __attribute__((ext_vector_type(8))) short s16x8;
typedef __attribute__((ext_vector_type(4))) float f32x4;
typedef __attribute__((ext_vector_type(2))) float f32x2;

__device__ inline unsigned short f2b(float f) {
    union { float f; unsigned int u; } v; v.f = f;
    unsigned int r = v.u + 0x7FFF + ((v.u >> 16) & 1);  // RNE
    return (unsigned short)(r >> 16);
}
__device__ inline float b2f(unsigned short u) {
    union { float f; unsigned int u; } v; v.u = ((unsigned int)u) << 16;
    return v.f;
}

// unpack 2 packed bf16 (one u32) -> f32x2 {elem0, elem1}; 2 VALU ops
__device__ __forceinline__ f32x2 unpk(unsigned int u) {
    union { unsigned int u; float f; } lo, hi;
    lo.u = u << 16;
    hi.u = u & 0xffff0000u;
    return f32x2{lo.f, hi.f};
}

// packed fma -> v_pk_fma_f32 (VOP3P); 1 issue for 2 lanes of math
__device__ __forceinline__ f32x2 pk_fma(f32x2 a, f32x2 b, f32x2 c) {
#if __has_builtin(__builtin_elementwise_fma)
    return __builtin_elementwise_fma(a, b, c);
#else
    return f32x2{fmaf(a.x, b.x, c.x), fmaf(a.y, b.y, c.y)};
#endif
}

// async 16B/lane global->LDS copy; lds base wave-uniform, lane i -> base+i*16
__device__ __forceinline__ void async16(const unsigned short* g, unsigned short* l) {
    __builtin_amdgcn_global_load_lds(
        (const __attribute__((address_space(1))) unsigned int*)g,
        (__attribute__((address_space(3))) unsigned int*)l, 16, 0, 0);
}

// R5: counted-vmcnt fences (T4). Memory clobber keeps LDS reads from
// hoisting above the wait; sched_barrier pins the boundary (rule #18).
#define WAITV(N) { asm volatile("s_waitcnt vmcnt(" #N ")" ::: "memory"); }
#define BAR()    { __builtin_amdgcn_s_barrier(); __builtin_amdgcn_sched_barrier(0); }

// ---------------------------------------------------------------------------
// prep: cast x to bf16 + cast+transpose weights to [N][K] bf16 via LDS-tiled
// 64x64 transpose (R2).
// ---------------------------------------------------------------------------
#define XCAST_BLOCKS 1568    // NTOK*256/8/256

__device__ __forceinline__ void transpose_tile(
    const float* __restrict__ src, unsigned short* __restrict__ dst,
    int K, int N, int kt, int nt, int tid, float* lds /*64x65*/)
{
    const int k0 = kt * 64, n0 = nt * 64;
    #pragma unroll
    for (int p = 0; p < 4; ++p) {               // read 16 k-rows x 64 n each
        const int r  = p * 16 + (tid >> 4);
        const int c4 = (tid & 15) * 4;
        const float4 v = *(const float4*)(src + (size_t)(k0 + r) * N + n0 + c4);
        lds[r * 65 + c4 + 0] = v.x; lds[r * 65 + c4 + 1] = v.y;
        lds[r * 65 + c4 + 2] = v.z; lds[r * 65 + c4 + 3] = v.w;
    }
    __syncthreads();
    #pragma unroll
    for (int p = 0; p < 4; ++p) {               // write 16 n-rows x 64 k each
        const int c  = p * 16 + (tid >> 4);
        const int k4 = (tid & 15) * 4;
        ushort4 o;
        o.x = f2b(lds[(k4 + 0) * 65 + c]);
        o.y = f2b(lds[(k4 + 1) * 65 + c]);
        o.z = f2b(lds[(k4 + 2) * 65 + c]);
        o.w = f2b(lds[(k4 + 3) * 65 + c]);
        *(ushort4*)(dst + (size_t)(n0 + c) * K + k0 + k4) = o;
    }
}

__global__ __launch_bounds__(256)
void prep_kernel(const float* __restrict__ x,
                 const float* __restrict__ Wq, const float* __restrict__ Wp,
                 const float* __restrict__ W1, const float* __restrict__ W2,
                 unsigned short* __restrict__ xb,
                 unsigned short* __restrict__ Wqb, unsigned short* __restrict__ Wpb,
                 unsigned short* __restrict__ W1b, unsigned short* __restrict__ W2b)
{
    __shared__ float lds[64 * 65];
    const int tid = threadIdx.x;
    if (blockIdx.x < XCAST_BLOCKS) {
        const int i = blockIdx.x * 256 + tid;   // 8 floats each
        const float4* xp = (const float4*)x + (size_t)i * 2;
        const float4 a = xp[0], b = xp[1];
        s16x8 o;
        o[0] = (short)f2b(a.x); o[1] = (short)f2b(a.y);
        o[2] = (short)f2b(a.z); o[3] = (short)f2b(a.w);
        o[4] = (short)f2b(b.x); o[5] = (short)f2b(b.y);
        o[6] = (short)f2b(b.z); o[7] = (short)f2b(b.w);
        *((s16x8*)xb + i) = o;
        return;
    }
    int wb = blockIdx.x - XCAST_BLOCKS;
    if (wb < 48) {                 // W_qkv: K=256, N=768 -> 4x12 tiles
        transpose_tile(Wq, Wqb, 256, 768, wb & 3, wb >> 2, tid, lds);
    } else if ((wb -= 48) < 16) {  // W_proj: K=256, N=256 -> 4x4
        transpose_tile(Wp, Wpb, 256, 256, wb & 3, wb >> 2, tid, lds);
    } else if ((wb -= 16) < 64) {  // W1: K=256, N=1024 -> 4x16
        transpose_tile(W1, W1b, 256, 1024, wb & 3, wb >> 2, tid, lds);
    } else {                       // W2: K=1024, N=256 -> 16x4
        wb -= 64;
        transpose_tile(W2, W2b, 1024, 256, wb & 15, wb >> 4, tid, lds);
    }
}

// ---------------------------------------------------------------------------
// bf16 MFMA GEMM, 128x128 tile, 4 waves. R4: XOR-swizzled LDS (via
// pre-swizzled source), bijective XCD chunking, LDS-bounce epilogue.
// R5: counted-vmcnt pipeline (T4) — raw s_barrier + s_waitcnt vmcnt(8)
// keeps the next tile's 8 global_load_lds in flight across the barrier
// (the old __syncthreads drained vmcnt to 0, exposing full load latency
// every K-step; that is why R1's double-buffer was neutral).
// Schedule/step: wait(own buf) -> bar -> compute(buf) -> bar -> stage(t+2).
// ---------------------------------------------------------------------------
__global__ __launch_bounds__(256)
void gemm_k(const unsigned short* __restrict__ Ab,
            const unsigned short* __restrict__ Bt, const float* __restrict__ bias,
            unsigned short* __restrict__ outb,
            int N, int K, int relu)
{
    __shared__ unsigned short As[2][128 * 64];   // 32 KB (reused as Cs in epilogue)
    __shared__ unsigned short Bs[2][128 * 64];   // 32 KB

    const int tid = threadIdx.x;

    // m204 bijective XCD chunk swizzle; desired ordering d is bm-major.
    const int nwg = gridDim.x;
    const int q8 = nwg >> 3, r8 = nwg & 7;
    const int xcd = blockIdx.x & 7, pos = blockIdx.x >> 3;
    const int d = (xcd < r8 ? xcd * (q8 + 1) : r8 * (q8 + 1) + (xcd - r8) * q8) + pos;
    const int nbx = N >> 7;                      // 128-wide col tiles
    const int bm = (d / nbx) * 128, bn = (d % nbx) * 128;

    const int wid = tid >> 6, lane = tid & 63;
    const int wm = (wid >> 1) * 64, wn = (wid & 1) * 64;
    const int row16 = lane & 15, quad = lane >> 4;
    const int crow = lane >> 3;
    const int ckS = ((lane & 7) ^ crow) * 8;     // XOR-swizzled source k-block

    f32x4 acc[4][4] = {};

    auto stage = [&](int buf, int k0) {          // 8 loads per wave
        #pragma unroll
        for (int c = 0; c < 4; ++c) {
            const int ch = wid * 4 + c;
            async16(Ab + (size_t)(bm + ch * 8 + crow) * K + k0 + ckS, As[buf] + ch * 512);
        }
        #pragma unroll
        for (int c = 0; c < 4; ++c) {
            const int ch = wid * 4 + c;
            async16(Bt + (size_t)(bn + ch * 8 + crow) * K + k0 + ckS, Bs[buf] + ch * 512);
        }
    };
    auto compute = [&](int buf) {
        #pragma unroll
        for (int kc = 0; kc < 2; ++kc) {
            s16x8 af[4], bf[4];
            #pragma unroll
            for (int i = 0; i < 4; ++i)
                af[i] = *(const s16x8*)(As[buf] + (wm + i * 16 + row16) * 64
                                        + (((kc * 4 + quad) ^ (row16 & 7)) * 8));
            #pragma unroll
            for (int j = 0; j < 4; ++j)
                bf[j] = *(const s16x8*)(Bs[buf] + (wn + j * 16 + row16) * 64
                                        + (((kc * 4 + quad) ^ (row16 & 7)) * 8));
            #pragma unroll
            for (int i = 0; i < 4; ++i)
                #pragma unroll
                for (int j = 0; j < 4; ++j)
                    acc[i][j] = __builtin_amdgcn_mfma_f32_16x16x32_bf16(af[i], bf[j], acc[i][j], 0, 0, 0);
        }
    };

    stage(0, 0);
    stage(1, 64);
    const int nsteps = K >> 6;                   // 4 (K=256)
    for (int s = 0; s < nsteps; ++s) {
        const int buf = s & 1;
        if (s == nsteps - 1) WAITV(0) else WAITV(8)     // own buf's 8 loads done
        BAR()                                           // all waves' loads landed
        compute(buf);
        BAR()                                           // all waves done reading buf
        if (s + 2 < nsteps) stage(buf, (s + 2) << 6);
    }

    // ---- epilogue: bias (+relu) -> bf16 via LDS bounce, coalesced stores
    unsigned short* Cs = (unsigned short*)As;    // 128x128 bf16 = 32 KB
    #pragma unroll
    for (int j = 0; j < 4; ++j) {
        const int col = wn + j * 16 + row16;
        const float bb = bias[bn + col];
        #pragma unroll
        for (int i = 0; i < 4; ++i) {
            const int rr = wm + i * 16 + quad * 4;
            #pragma unroll
            for (int reg = 0; reg < 4; ++reg) {
                float v = acc[i][j][reg] + bb;
                if (relu) v = fmaxf(v, 0.f);
                Cs[(rr + reg) * 128 + col] = f2b(v);
            }
        }
    }
    __syncthreads();
    #pragma unroll
    for (int p = 0; p < 8; ++p) {
        const int s = p * 256 + tid;             // 2048 x 16B chunks
        const int rr = s >> 4, cb = (s & 15) * 8;
        *(s16x8*)(outb + (size_t)(bm + rr) * N + bn + cb) = *(const s16x8*)(Cs + rr * 128 + cb);
    }
}

// ---------------------------------------------------------------------------
// Fused GEMM (N=256 full-row tile) + residual add + LayerNorm.
// BM=64, 512 threads (8 waves, 2m x 4n), XOR-swizzled LDS (R4).
// R5: counted-vmcnt pipeline, 5 loads/wave/stage -> vmcnt(5).
// ---------------------------------------------------------------------------
__global__ __launch_bounds__(512)
void gemm_ln(const unsigned short* __restrict__ Ab, const unsigned short* __restrict__ Bt,
             const float* __restrict__ bias, const float* __restrict__ resid,
             const float* __restrict__ g, const float* __restrict__ beta,
             float* __restrict__ outf, unsigned short* __restrict__ outb, int K)
{
    __shared__ unsigned short As[2][64 * 64];    // 16 KB (buf0 reused for LN reduce)
    __shared__ unsigned short Bs[2][256 * 64];   // 64 KB

    const int tid = threadIdx.x;
    const int bm = blockIdx.x * 64;
    const int wid = tid >> 6, lane = tid & 63;
    const int wm = (wid >> 2) * 32, wn = (wid & 3) * 64;
    const int wc = wid & 3;
    const int row16 = lane & 15, quad = lane >> 4;
    const int crow = lane >> 3;
    const int ckS = ((lane & 7) ^ crow) * 8;     // XOR-swizzled source k-block

    f32x4 acc[2][4] = {};

    auto stage = [&](int buf, int k0) {          // 5 loads per wave
        #pragma unroll
        for (int c = 0; c < 5; ++c) {
            const int ch = wid * 5 + c;
            if (ch < 8) {
                async16(Ab + (size_t)(bm + ch * 8 + crow) * K + k0 + ckS, As[buf] + ch * 512);
            } else {
                const int bc = ch - 8;
                async16(Bt + (size_t)(bc * 8 + crow) * K + k0 + ckS, Bs[buf] + bc * 512);
            }
        }
    };
    auto compute = [&](int buf) {
        #pragma unroll
        for (int kc = 0; kc < 2; ++kc) {
            s16x8 af[2], bf[4];
            #pragma unroll
            for (int i = 0; i < 2; ++i)
                af[i] = *(const s16x8*)(As[buf] + (wm + i * 16 + row16) * 64
                                        + (((kc * 4 + quad) ^ (row16 & 7)) * 8));
            #pragma unroll
            for (int j = 0; j < 4; ++j)
                bf[j] = *(const s16x8*)(Bs[buf] + (wn + j * 16 + row16) * 64
                                        + (((kc * 4 + quad) ^ (row16 & 7)) * 8));
            #pragma unroll
            for (int i = 0; i < 2; ++i)
                #pragma unroll
                for (int j = 0; j < 4; ++j)
                    acc[i][j] = __builtin_amdgcn_mfma_f32_16x16x32_bf16(af[i], bf[j], acc[i][j], 0, 0, 0);
        }
    };

    stage(0, 0);
    stage(1, 64);
    const int nsteps = K >> 6;                   // 4 or 16
    for (int s = 0; s < nsteps; ++s) {
        const int buf = s & 1;
        if (s == nsteps - 1) WAITV(0) else WAITV(5)
        BAR()
        compute(buf);
        BAR()
        if (s + 2 < nsteps) stage(buf, (s + 2) << 6);
    }

    // ---- epilogue: bias + residual, in-register
    float bb[4], gv[4], bev[4];
    #pragma unroll
    for (int j = 0; j < 4; ++j) {
        const int col = wn + j * 16 + row16;
        bb[j] = bias[col]; gv[j] = g[col]; bev[j] = beta[col];
    }
    #pragma unroll
    for (int i = 0; i < 2; ++i) {
        #pragma unroll
        for (int reg = 0; reg < 4; ++reg) {
            const size_t rb = (size_t)(bm + wm + i * 16 + quad * 4 + reg) * 256;
            #pragma unroll
            for (int j = 0; j < 4; ++j)
                acc[i][j][reg] += bb[j] + resid[rb + wn + j * 16 + row16];
        }
    }

    // ---- per-row sum / sumsq: reduce across row16 (16 lanes), then LDS
    float* red = (float*)As[0];           // [64 rows][4 col-waves][2]
    #pragma unroll
    for (int i = 0; i < 2; ++i) {
        #pragma unroll
        for (int reg = 0; reg < 4; ++reg) {
            float s1 = 0.f, s2 = 0.f;
            #pragma unroll
            for (int j = 0; j < 4; ++j) {
                const float t = acc[i][j][reg];
                s1 += t; s2 += t * t;
            }
            #pragma unroll
            for (int o = 1; o < 16; o <<= 1) {
                s1 += __shfl_xor(s1, o, 64);
                s2 += __shfl_xor(s2, o, 64);
            }
            if (row16 == 0) {
                const int lrow = wm + i * 16 + quad * 4 + reg;
                red[lrow * 8 + wc * 2]     = s1;
                red[lrow * 8 + wc * 2 + 1] = s2;
            }
        }
    }
    __syncthreads();
    float* stats = red + 512;             // [64][2] = m, invstd
    if (tid < 64) {
        const float S1 = red[tid*8] + red[tid*8+2] + red[tid*8+4] + red[tid*8+6];
        const float S2 = red[tid*8+1] + red[tid*8+3] + red[tid*8+5] + red[tid*8+7];
        const float m = S1 * (1.0f / 256.0f);
        const float var = S2 * (1.0f / 256.0f) - m * m;
        stats[tid * 2]     = m;
        stats[tid * 2 + 1] = rsqrtf(var + 1e-5f);
    }
    __syncthreads();

    // ---- normalize + store
    #pragma unroll
    for (int i = 0; i < 2; ++i) {
        #pragma unroll
        for (int reg = 0; reg < 4; ++reg) {
            const int lrow = wm + i * 16 + quad * 4 + reg;
            const float m = stats[lrow * 2], r = stats[lrow * 2 + 1];
            const size_t rb = (size_t)(bm + lrow) * 256;
            #pragma unroll
            for (int j = 0; j < 4; ++j) {
                const int col = wn + j * 16 + row16;
                const float o = (acc[i][j][reg] - m) * r * gv[j] + bev[j];
                outf[rb + col] = o;
                if (outb) outb[rb + col] = f2b(o);
            }
        }
    }
}

// ---------------------------------------------------------------------------
// Tiled neighborhood attention: block = (16x16 tile, head), 256 threads,
// 1 query/lane; K,V halo in LDS; fused no-max softmax; packed bf16 unpack
// + v_pk_fma_f32 (R0).
// ---------------------------------------------------------------------------
__global__ __launch_bounds__(256, 2)
void natt_kernel(const unsigned short* __restrict__ qkvb, unsigned short* __restrict__ att)
{
    const int blk  = blockIdx.x;          // 4*16*8 = 512
    const int head = blk & 7;
    const int t2   = blk >> 3;
    const int tile = t2 & 15;
    const int b    = t2 >> 4;
    const int r0 = (tile >> 2) * 16, c0 = (tile & 3) * 16;
    const int hs = min(max(r0 - 3, 0), 34);
    const int ws = min(max(c0 - 3, 0), 34);

    __shared__ unsigned short Ks[NHTOK * KV_PAD];
    __shared__ unsigned short Vs[NHTOK * KV_PAD];

    const int tid = threadIdx.x;

    #pragma unroll
    for (int it = 0; it < 8; ++it) {
        const int t = it * 64 + (tid >> 2);
        if (t < NHTOK) {
            const int hr = t / HALO, hc = t - hr * HALO;
            const size_t rb = ((size_t)((b * 56 + hs + hr) * 56 + (ws + hc))) * 768;
            const int d8 = (tid & 3) * 8;
            *(s16x8*)(Ks + t * KV_PAD + d8) = *(const s16x8*)(qkvb + rb + 256 + head * 32 + d8);
            *(s16x8*)(Vs + t * KV_PAD + d8) = *(const s16x8*)(qkvb + rb + 512 + head * 32 + d8);
        }
    }

    const int qh = min(r0 + (tid >> 4), 55);
    const int qw = min(c0 + (tid & 15), 55);
    const int tok = (b * 56 + qh) * 56 + qw;
    const int ro = min(max(qh - 3, 0), 49) - hs;
    const int co = min(max(qw - 3, 0), 49) - ws;

    f32x2 qf[16];
    {
        const unsigned int* qp = (const unsigned int*)(qkvb + (size_t)tok * 768 + head * 32);
        #pragma unroll
        for (int p = 0; p < 16; ++p)
            qf[p] = unpk(qp[p]) * 0.17677669529663687f;
    }
    __syncthreads();

    f32x2 acc[16] = {};
    float sum = 0.f;
    for (int i = 0; i < 7; ++i) {
        const int trow = (ro + i) * HALO + co;
        #pragma unroll
        for (int j = 0; j < 7; ++j) {
            const unsigned int* kp = (const unsigned int*)(Ks + (trow + j) * KV_PAD);
            const unsigned int* vp = (const unsigned int*)(Vs + (trow + j) * KV_PAD);
            const uint4 ka = *(const uint4*)(kp);
            const uint4 kb = *(const uint4*)(kp + 4);
            const uint4 kc = *(const uint4*)(kp + 8);
            const uint4 kd = *(const uint4*)(kp + 12);
            const uint4 va = *(const uint4*)(vp);
            const uint4 vb = *(const uint4*)(vp + 4);
            const uint4 vc = *(const uint4*)(vp + 8);
            const uint4 vd = *(const uint4*)(vp + 12);
            // QK dot: 16 pk_fma, two parallel chains (8 deep each)
            f32x2 sa = {0.f, 0.f}, sb = {0.f, 0.f};
            sa = pk_fma(qf[0],  unpk(ka.x), sa);  sb = pk_fma(qf[1],  unpk(ka.y), sb);
            sa = pk_fma(qf[2],  unpk(ka.z), sa);  sb = pk_fma(qf[3],  unpk(ka.w), sb);
            sa = pk_fma(qf[4],  unpk(kb.x), sa);  sb = pk_fma(qf[5],  unpk(kb.y), sb);
            sa = pk_fma(qf[6],  unpk(kb.z), sa);  sb = pk_fma(qf[7],  unpk(kb.w), sb);
            sa = pk_fma(qf[8],  unpk(kc.x), sa);  sb = pk_fma(qf[9],  unpk(kc.y), sb);
            sa = pk_fma(qf[10], unpk(kc.z), sa);  sb = pk_fma(qf[11], unpk(kc.w), sb);
            sa = pk_fma(qf[12], unpk(kd.x), sa);  sb = pk_fma(qf[13], unpk(kd.y), sb);
            sa = pk_fma(qf[14], unpk(kd.z), sa);  sb = pk_fma(qf[15], unpk(kd.w), sb);
            const float p = __expf(sa.x + sa.y + sb.x + sb.y);
            sum += p;
            const f32x2 pv = {p, p};
            acc[0]  = pk_fma(pv, unpk(va.x), acc[0]);
            acc[1]  = pk_fma(pv, unpk(va.y), acc[1]);
            acc[2]  = pk_fma(pv, unpk(va.z), acc[2]);
            acc[3]  = pk_fma(pv, unpk(va.w), acc[3]);
            acc[4]  = pk_fma(pv, unpk(vb.x), acc[4]);
            acc[5]  = pk_fma(pv, unpk(vb.y), acc[5]);
            acc[6]  = pk_fma(pv, unpk(vb.z), acc[6]);
            acc[7]  = pk_fma(pv, unpk(vb.w), acc[7]);
            acc[8]  = pk_fma(pv, unpk(vc.x), acc[8]);
            acc[9]  = pk_fma(pv, unpk(vc.y), acc[9]);
            acc[10] = pk_fma(pv, unpk(vc.z), acc[10]);
            acc[11] = pk_fma(pv, unpk(vc.w), acc[11]);
            acc[12] = pk_fma(pv, unpk(vd.x), acc[12]);
            acc[13] = pk_fma(pv, unpk(vd.y), acc[13]);
            acc[14] = pk_fma(pv, unpk(vd.z), acc[14]);
            acc[15] = pk_fma(pv, unpk(vd.w), acc[15]);
        }
    }
    const float inv = 1.0f / sum;

    unsigned short* op = att + (size_t)tok * DMODEL + head * 32;
    #pragma unroll
    for (int d4 = 0; d4 < 8; ++d4) {
        ushort4 o;
        o.x = f2b(acc[d4 * 2].x     * inv);
        o.y = f2b(acc[d4 * 2].y     * inv);
        o.z = f2b(acc[d4 * 2 + 1].x * inv);
        o.w = f2b(acc[d4 * 2 + 1].y * inv);
        *(ushort4*)(op + d4 * 4) = o;
    }
}

// ---------------------------------------------------------------------------
extern "C" void kernel_launch(void* const* d_in, const int* in_sizes, int n_in,
                              void* d_out, int out_size, void* d_ws, size_t ws_size,
                              hipStream_t stream)
{
    const float* x      = (const float*)d_in[0];
    const float* W_qkv  = (const float*)d_in[1];
    const float* b_qkv  = (const float*)d_in[2];
    const float* W_proj = (const float*)d_in[3];
    const float* b_proj = (const float*)d_in[4];
    const float* W1     = (const float*)d_in[5];
    const float* b1     = (const float*)d_in[6];
    const float* W2     = (const float*)d_in[7];
    const float* b2     = (const float*)d_in[8];
    const float* g1     = (const float*)d_in[9];
    const float* be1    = (const float*)d_in[10];
    const float* g2     = (const float*)d_in[11];
    const float* be2    = (const float*)d_in[12];
    float* out = (float*)d_out;

    char* ws = (char*)d_ws;
    const int M = NTOK;  // 12544

    unsigned short* qkvb = (unsigned short*)ws;                     // [M][768] bf16
    unsigned short* h    = (unsigned short*)ws;                     // [M][1024] bf16 (after qkvb dead)
    unsigned short* attb = (unsigned short*)(ws + 38535168);        // [M][256] bf16
    float*          xn   = (float*)(ws + 57802752);                 // [M][256] f32
    unsigned short* xnb  = (unsigned short*)(ws + 70647808);        // [M][256] bf16
    unsigned short* Wqb  = (unsigned short*)(ws + 77070336);
    unsigned short* Wpb  = Wqb + 196608;
    unsigned short* W1b  = Wpb + 65536;
    unsigned short* W2b  = W1b + 262144;
    unsigned short* xb   = (unsigned short*)(ws + 78643200);        // [M][256] bf16

    dim3 blk(256);

    // 0) cast x to bf16 + cast/transpose weights to bf16 (tiled transpose)
    prep_kernel<<<dim3(XCAST_BLOCKS + 48 + 16 + 64 + 64), blk, 0, stream>>>(
        x, W_qkv, W_proj, W1, W2, xb, Wqb, Wpb, W1b, W2b);

    // 1) qkvb = bf16(xb @ W_qkv + b_qkv)   (588 blocks, XCD-chunked)
    gemm_k<<<dim3(6 * 98), blk, 0, stream>>>(xb, Wqb, b_qkv, qkvb, 768, 256, 0);

    // 2) tiled neighborhood attention -> attb
    natt_kernel<<<dim3(512), blk, 0, stream>>>(qkvb, attb);

    // 3+4) xn = LN(x + attb @ W_proj + b_proj)  (f32 + bf16), fused
    gemm_ln<<<dim3(M / 64), dim3(512), 0, stream>>>(attb, Wpb, b_proj, x, g1, be1, xn, xnb, 256);

    // 5) h = relu(xnb @ W1 + b1)  (bf16, 784 blocks, XCD-chunked)
    gemm_k<<<dim3(8 * 98), blk, 0, stream>>>(xnb, W1b, b1, h, 1024, 256, 1);

    // 6+7) out = LN(xn + h @ W2 + b2), fused
    gemm_ln<<<dim3(M / 64), dim3(512), 0, stream>>>(h, W2b, b2, xn, g2, be2, out, nullptr, 1024);
}